// Round 6
// baseline (1045.855 us; speedup 1.0000x reference)
//
#include <hip/hip_runtime.h>
#include <hip/hip_bf16.h>

// Dims
#define BB 256
#define LL 128
#define AA 39
#define BDD 10
#define KK 6
#define MM 256
#define FP 256
#define RR 3
#define TT 2

using short8  = __attribute__((ext_vector_type(8))) short;
using short4v = __attribute__((ext_vector_type(4))) short;
using f32x4   = __attribute__((ext_vector_type(4))) float;
using f32x2   = __attribute__((ext_vector_type(2))) float;

__device__ __forceinline__ short f2bf(float f) {
    union { float f; unsigned u; } v; v.f = f;
    unsigned u = v.u;
    u += 0x7fffu + ((u >> 16) & 1u);   // round-to-nearest-even
    return (short)(u >> 16);
}
__device__ __forceinline__ float bf2f(short s) {
    union { unsigned u; float f; } v; v.u = ((unsigned)(unsigned short)s) << 16;
    return v.f;
}
__device__ __forceinline__ float wred64(float v) {
#pragma unroll
    for (int off = 32; off >= 1; off >>= 1) v += __shfl_xor(v, off);
    return v;
}

// ---------------- transpose: dst[i*O+o] = src[o*I+i] ----------------
__global__ __launch_bounds__(256) void k_transpose(const float* __restrict__ src,
                                                   float* __restrict__ dst, int O, int I) {
    int idx = blockIdx.x * 256 + threadIdx.x;
    if (idx >= O * I) return;
    int o = idx / I, i = idx - o * I;
    dst[i * O + o] = src[idx];
}

// ---------------- pack ALL GRU weights into MFMA fragment-major bf16 ----------------
// out layout: [d][mat][ks(8)][nt(48)][lane(64)][j(8)]
__global__ __launch_bounds__(256) void k_prep_gruw(const float* __restrict__ gwih,
                                                   const float* __restrict__ gwhh,
                                                   short* __restrict__ out) {
    int idx = blockIdx.x * 256 + threadIdx.x;
    if (idx >= RR * 2 * 8 * 48 * 512) return;
    int j = idx & 7;
    int lane = (idx >> 3) & 63;
    int blk = idx >> 9;
    int nt = blk % 48;
    int ks = (blk / 48) % 8;
    int mat = (blk / (48 * 8)) % 2;
    int d = blk / (48 * 8 * 2);
    int n = nt * 16 + (lane & 15);
    int k = ks * 32 + (lane >> 4) * 8 + j;
    const float* W = mat ? gwhh : gwih;
    out[idx] = f2bf(W[((size_t)d * 768 + n) * FP + k]);
}

// ---------------- pack ALL attend weights: [d][ks(8)][nt(16)][lane][j] ----------------
__global__ __launch_bounds__(256) void k_prep_waf(const float* __restrict__ atW,
                                                  short* __restrict__ out) {
    int idx = blockIdx.x * 256 + threadIdx.x;
    if (idx >= RR * 8 * 16 * 512) return;
    int j = idx & 7;
    int lane = (idx >> 3) & 63;
    int blk = idx >> 9;
    int nt = blk % 16;
    int ks = (blk / 16) % 8;
    int d = blk / 128;
    int n = nt * 16 + (lane & 15);
    int k = ks * 32 + (lane >> 4) * 8 + j;
    out[idx] = f2bf(atW[(size_t)d * FP * FP + (size_t)n * FP + k]);
}

// ---------------- atom fc (8 atoms/block) ----------------
__global__ __launch_bounds__(256) void k_atom_fc8(const float* __restrict__ atom_list,
                                                  const float* __restrict__ WafcT,
                                                  const float* __restrict__ bias,
                                                  float* __restrict__ out_pre,
                                                  float* __restrict__ hbuf,
                                                  short* __restrict__ hb16) {
    int g0 = blockIdx.x * 8;
    int t = threadIdx.x;
    __shared__ float x[8][AA];
    for (int i = t; i < 8 * AA; i += 256) x[i / AA][i % AA] = atom_list[(size_t)g0 * AA + i];
    __syncthreads();
    float acc[8];
    float bv = bias[t];
#pragma unroll
    for (int a = 0; a < 8; ++a) acc[a] = bv;
    for (int i = 0; i < AA; ++i) {
        float w = WafcT[i * FP + t];
#pragma unroll
        for (int a = 0; a < 8; ++a) acc[a] += x[a][i] * w;
    }
#pragma unroll
    for (int a = 0; a < 8; ++a) {
        size_t idx = (size_t)(g0 + a) * FP + t;
        out_pre[idx] = acc[a];
        float rl = fmaxf(acc[a], 0.f);
        hbuf[idx] = rl;
        hb16[idx] = f2bf(rl);   // h0 = relu(pre); also ACT source for d=0
    }
}

// ---------------- ApreB = bf16(atom_list @ WnA^T + bn) ----------------
__global__ __launch_bounds__(256) void k_apre(const float* __restrict__ atom_list,
                                              const float* __restrict__ WnT,
                                              const float* __restrict__ bn,
                                              short* __restrict__ ApreB) {
    int g0 = blockIdx.x * 8;
    int t = threadIdx.x;
    __shared__ float x[8][AA];
    for (int i = t; i < 8 * AA; i += 256) x[i / AA][i % AA] = atom_list[(size_t)g0 * AA + i];
    __syncthreads();
    float acc[8];
    float bv = bn[t];
#pragma unroll
    for (int a = 0; a < 8; ++a) acc[a] = bv;
    for (int i = 0; i < AA; ++i) {
        float w = WnT[i * FP + t];
#pragma unroll
        for (int a = 0; a < 8; ++a) acc[a] += x[a][i] * w;
    }
#pragma unroll
    for (int a = 0; a < 8; ++a) ApreB[(size_t)(g0 + a) * FP + t] = f2bf(acc[a]);
}

// ---------------- attention: per-molecule LDS-staged gather ----------------
// 2 blocks / molecule (512 thr each, 8 waves x 8 atoms); full 64KB slab staged.
template<int IS_D0>
__global__ __launch_bounds__(512) void k_awn2(
        const short* __restrict__ ACTB,     // relu'd act bf16 (self dots)
        const short* __restrict__ SRC,      // neighbor source to stage
        const float* __restrict__ bond_list,
        const int* __restrict__ adeg, const int* __restrict__ bdeg,
        const float* __restrict__ WnT,      // bond rows AA..AA+BDD-1 (d0 only)
        const float* __restrict__ alignW, const float* __restrict__ alignBp,
        short* __restrict__ wn_out, float* __restrict__ sw_out,
        float* __restrict__ awv_out) {
    __shared__ short snb[LL * FP];          // 64 KB
    const int b = blockIdx.x >> 1;
    const int half = blockIdx.x & 1;
    const int t = threadIdx.x;
    const int wave = t >> 6, lane = t & 63;

    // stage whole molecule slab (64KB) via global_load_lds width-16
    {
        const char* src = (const char*)(SRC + (size_t)b * LL * FP);
#pragma unroll
        for (int it = 0; it < 8; ++it) {
            int off = it * 8192 + wave * 1024 + lane * 16;
            __builtin_amdgcn_global_load_lds(
                (const __attribute__((address_space(1))) void*)(src + off),
                (__attribute__((address_space(3))) void*)((char*)snb + it * 8192 + wave * 1024),
                16, 0, 0);
        }
    }

    f32x4 w0 = *(const f32x4*)(alignW + lane * 4);
    f32x4 w1 = *(const f32x4*)(alignW + FP + lane * 4);
    float bias = alignBp[0];

    float wnt[IS_D0 ? BDD : 1][4];
    if constexpr (IS_D0) {
#pragma unroll
        for (int i = 0; i < BDD; ++i) {
            f32x4 v = *(const f32x4*)(WnT + (AA + i) * FP + lane * 4);
#pragma unroll
            for (int q = 0; q < 4; ++q) wnt[i][q] = v[q];
        }
    }

    __syncthreads();   // staging complete

#pragma unroll
    for (int ai = 0; ai < 8; ++ai) {
        const int al = half * 64 + wave * 8 + ai;
        const int ga = b * LL + al;

        short4v sv = *(const short4v*)(ACTB + (size_t)ga * FP + lane * 4);
        float ss = wred64(bf2f(sv[0]) * w0[0] + bf2f(sv[1]) * w0[1] +
                          bf2f(sv[2]) * w0[2] + bf2f(sv[3]) * w0[3]);

        int jx[KK];
#pragma unroll
        for (int k = 0; k < KK; ++k) jx[k] = adeg[ga * KK + k];

        float nf[KK][4];
        float sc[KK];
#pragma unroll
        for (int k = 0; k < KK; ++k) {
            short4v nv = *(const short4v*)(snb + jx[k] * FP + lane * 4);
            float f0 = bf2f(nv[0]), f1 = bf2f(nv[1]), f2 = bf2f(nv[2]), f3 = bf2f(nv[3]);
            if constexpr (IS_D0) {
                int bi = bdeg[ga * KK + k];
                const float* bp = bond_list + ((size_t)b * MM + bi) * BDD;
                float bb[BDD];
#pragma unroll
                for (int i = 0; i < 5; ++i) {
                    f32x2 v2 = *(const f32x2*)(bp + 2 * i);
                    bb[2 * i] = v2[0]; bb[2 * i + 1] = v2[1];
                }
                float b0 = 0.f, b1 = 0.f, b2 = 0.f, b3 = 0.f;
#pragma unroll
                for (int i = 0; i < BDD; ++i) {
                    b0 += bb[i] * wnt[i][0]; b1 += bb[i] * wnt[i][1];
                    b2 += bb[i] * wnt[i][2]; b3 += bb[i] * wnt[i][3];
                }
                f0 = fmaxf(f0 + b0, 0.f); f1 = fmaxf(f1 + b1, 0.f);
                f2 = fmaxf(f2 + b2, 0.f); f3 = fmaxf(f3 + b3, 0.f);
            }
            nf[k][0] = f0; nf[k][1] = f1; nf[k][2] = f2; nf[k][3] = f3;
            float s2 = wred64(f0 * w1[0] + f1 * w1[1] + f2 * w1[2] + f3 * w1[3]);
            float s = fmaxf(ss + s2 + bias, 0.f);
            if (jx[k] == LL - 1) s -= 9.0f;
            sc[k] = s;
        }

        float m = sc[0];
#pragma unroll
        for (int k = 1; k < KK; ++k) m = fmaxf(m, sc[k]);
        float e[KK], den = 0.f;
#pragma unroll
        for (int k = 0; k < KK; ++k) { e[k] = expf(sc[k] - m); den += e[k]; }
        float aw[KK], sumaw = 0.f;
#pragma unroll
        for (int k = 0; k < KK; ++k) {
            aw[k] = (jx[k] == LL - 1) ? 0.f : e[k] / den;
            sumaw += aw[k];
        }
        if (lane < KK) {
            float av = aw[0];
#pragma unroll
            for (int k = 1; k < KK; ++k) if (lane == k) av = aw[k];
            awv_out[(size_t)ga * KK + lane] = av;
        }
        if (lane == 0) sw_out[ga] = sumaw;

        short4v wo;
#pragma unroll
        for (int q = 0; q < 4; ++q) {
            float w = 0.f;
#pragma unroll
            for (int k = 0; k < KK; ++k) w += aw[k] * nf[k][q];
            wo[q] = f2bf(w);
        }
        *(short4v*)(wn_out + (size_t)ga * FP + lane * 4) = wo;
    }
}

// ---------------- ctx = relu(WN @ Wa^T + sumaw*ab), LDS-staged B, ks-stagger ----
__global__ __launch_bounds__(512) void k_ctx_mfma(
        const short* __restrict__ XB,      // wn bf16
        const float* __restrict__ SW,
        const short* __restrict__ WaF,     // frag-major (8,16,64,8)
        const float* __restrict__ ab,
        short* __restrict__ ctx_out) {
    __shared__ short lds[2][8192];         // 2 x 16KB
    const int t = threadIdx.x;
    const int wave = t >> 6, lane = t & 63;
    const int abase = blockIdx.x * 32 + (wave >> 2) * 16;
    const int wn4 = wave & 3;
    const int lr = lane & 15, lk = lane >> 4;
    const int kofs = blockIdx.x & 7;

#define CSTAGE(i) do { \
        int ke_ = ((i) + kofs) & 7; \
        _Pragma("unroll") \
        for (int e = 0; e < 2; ++e) { \
            int f = wave * 2 + e; \
            __builtin_amdgcn_global_load_lds( \
                (const __attribute__((address_space(1))) void*)(WaF + (size_t)(ke_ * 16 + f) * 512 + lane * 8), \
                (__attribute__((address_space(3))) void*)(&lds[(i) & 1][f * 512]), 16, 0, 0); \
        } } while (0)

    f32x4 acc[4] = {};
    const short8* xrow = (const short8*)(XB + (size_t)(abase + lr) * FP);

    CSTAGE(0);
#pragma unroll
    for (int i = 0; i < 8; ++i) {
        int ke = (i + kofs) & 7;
        short8 ax = xrow[ke * 4 + lk];
        __syncthreads();
        if (i < 7) CSTAGE(i + 1);
#pragma unroll
        for (int sub = 0; sub < 4; ++sub) {
            int nt = wn4 * 4 + sub;
            short8 bf = *(const short8*)(&lds[i & 1][nt * 512 + lane * 8]);
            acc[sub] = __builtin_amdgcn_mfma_f32_16x16x32_bf16(ax, bf, acc[sub], 0, 0, 0);
        }
    }
#undef CSTAGE

#pragma unroll
    for (int sub = 0; sub < 4; ++sub) {
        int c = wn4 * 64 + sub * 16 + lr;
        float abc = ab[c];
#pragma unroll
        for (int q = 0; q < 4; ++q) {
            int atom = abase + lk * 4 + q;
            float v = acc[sub][q] + SW[atom] * abc;
            ctx_out[(size_t)atom * FP + c] = f2bf(fmaxf(v, 0.f));
        }
    }
}

// ---------------- fused MFMA GRU: 24KB half-phase dbuf, ks-stagger, 4 chunks ----
// 256 blocks x 512 thr; each block does 4 chunks of 32 atoms.
template<int LAST>
__global__ __launch_bounds__(512) void k_gru_mfma(
        const short* __restrict__ XB,     // ctx bf16
        const short* __restrict__ HBl,    // h bf16 (read)
        float* __restrict__ hbuf,         // h fp32 (read old, write new)
        const short* __restrict__ Bih,    // frag-major (8,48,64,8)
        const short* __restrict__ Bhh,
        const float* __restrict__ bih, const float* __restrict__ bhh,
        float* __restrict__ act_out,
        short* __restrict__ HB_out,
        short* __restrict__ ACT_out) {
    __shared__ short lds[2][12288];       // 2 x 24KB
    const int t = threadIdx.x;
    const int wave = t >> 6, lane = t & 63;
    const int wn = wave & 3;
    const int lr = lane & 15, lk = lane >> 4;
    const int bid = blockIdx.x;
    const int kofs = bid & 7;

// phase p in [0,32): ks=(p>>2)+kofs (mod 8), mat=(p>>1)&1, h=p&1
// stage 24 frags (sub in {2h,2h+1}) into lds[p&1]
#define PKS(p)  ((((p) >> 2) + kofs) & 7)
#define STAGEP(p) do { \
        const short* base_ = ((((p) >> 1) & 1) ? Bhh : Bih) + (size_t)PKS(p) * 24576; \
        const int h_ = (p) & 1; \
        _Pragma("unroll") \
        for (int e = 0; e < 3; ++e) { \
            int j = wave * 3 + e; \
            int nt = 4 * (j >> 1) + 2 * h_ + (j & 1); \
            __builtin_amdgcn_global_load_lds( \
                (const __attribute__((address_space(1))) void*)(base_ + nt * 512 + lane * 8), \
                (__attribute__((address_space(3))) void*)(&lds[(p) & 1][j * 512]), 16, 0, 0); \
        } } while (0)

    for (int chunk = 0; chunk < 4; ++chunk) {
        const int abase = bid * 128 + chunk * 32 + (wave >> 2) * 16;
        const short8* xrow = (const short8*)(XB + (size_t)(abase + lr) * FP);
        const short8* hrow = (const short8*)(HBl + (size_t)(abase + lr) * FP);
        f32x4 acc_i[12] = {};
        f32x4 acc_h[12] = {};

        if (chunk) __syncthreads();   // prior chunk's last reads done before restage
        STAGEP(0);
        short8 ax{}, ah{};
#pragma unroll
        for (int p = 0; p < 32; ++p) {
            const int h_ = p & 1;
            if ((p & 3) == 0) {
                int ke = PKS(p);
                ax = xrow[ke * 4 + lk];
                ah = hrow[ke * 4 + lk];
            }
            __syncthreads();          // lds[p&1] staged; prev reads of lds[(p+1)&1] done
            if (p < 31) STAGEP(p + 1);
            const short8 a8 = ((p >> 1) & 1) ? ah : ax;
#pragma unroll
            for (int g = 0; g < 3; ++g) {
#pragma unroll
                for (int s2 = 0; s2 < 2; ++s2) {
                    const int sub = 2 * h_ + s2;
                    const int j = ((4 * g + wn) << 1) | s2;
                    short8 bf = *(const short8*)(&lds[p & 1][j * 512 + lane * 8]);
                    if ((p >> 1) & 1)
                        acc_h[g * 4 + sub] = __builtin_amdgcn_mfma_f32_16x16x32_bf16(a8, bf, acc_h[g * 4 + sub], 0, 0, 0);
                    else
                        acc_i[g * 4 + sub] = __builtin_amdgcn_mfma_f32_16x16x32_bf16(a8, bf, acc_i[g * 4 + sub], 0, 0, 0);
                }
            }
        }
        __syncthreads();   // all HBl reads of this chunk done before HB_out writes

#pragma unroll
        for (int sub = 0; sub < 4; ++sub) {
            int c = wn * 64 + sub * 16 + lr;
            float bir = bih[c], biz = bih[FP + c], bin_ = bih[2 * FP + c];
            float bhr = bhh[c], bhz = bhh[FP + c], bhn = bhh[2 * FP + c];
#pragma unroll
            for (int q = 0; q < 4; ++q) {
                int atom = abase + lk * 4 + q;
                size_t idx = (size_t)atom * FP + c;
                float hold = hbuf[idx];
                float r = 1.f / (1.f + expf(-(acc_i[0 * 4 + sub][q] + bir + acc_h[0 * 4 + sub][q] + bhr)));
                float z = 1.f / (1.f + expf(-(acc_i[1 * 4 + sub][q] + biz + acc_h[1 * 4 + sub][q] + bhz)));
                float n = tanhf(acc_i[2 * 4 + sub][q] + bin_ + r * (acc_h[2 * 4 + sub][q] + bhn));
                float hn = (1.f - z) * n + z * hold;
                float rl = fmaxf(hn, 0.f);
                hbuf[idx] = hn;
                act_out[idx] = rl;
                if constexpr (!LAST) {
                    HB_out[idx] = f2bf(hn);
                    ACT_out[idx] = f2bf(rl);
                }
            }
        }
    }
#undef STAGEP
#undef PKS
}

// ---------------- mol reductions ----------------
__global__ __launch_bounds__(256) void k_mol_reduce(const float* __restrict__ hbuf,
                                                    const float* __restrict__ act,
                                                    const float* __restrict__ mask,
                                                    float* __restrict__ o_unb0,
                                                    float* __restrict__ o_mfv0,
                                                    float* __restrict__ molF) {
    int b = blockIdx.x, t = threadIdx.x;
    float s1 = 0.f, s2 = 0.f;
    for (int l = 0; l < LL; ++l) {
        float mk = mask[b * LL + l];
        s1 += hbuf[((size_t)b * LL + l) * FP + t] * mk;
        s2 += act[((size_t)b * LL + l) * FP + t] * mk;
    }
    o_unb0[b * FP + t] = s1;
    o_mfv0[b * FP + t] = s2;
    molF[b * FP + t] = s2;
}

// ---------------- AV = act @ mol_attend_W.T + b ----------------
__global__ __launch_bounds__(256) void k_av(const float* __restrict__ act,
                                            const float* __restrict__ MWaT,
                                            const float* __restrict__ mab,
                                            float* __restrict__ AV) {
    int g0 = blockIdx.x * 8;
    int t = threadIdx.x;
    __shared__ float xs[8][FP];
    for (int a = 0; a < 8; ++a) xs[a][t] = act[(size_t)(g0 + a) * FP + t];
    __syncthreads();
    float acc[8];
    float bb2 = mab[t];
#pragma unroll
    for (int a = 0; a < 8; ++a) acc[a] = bb2;
    for (int i = 0; i < FP; ++i) {
        float w = MWaT[i * FP + t];
#pragma unroll
        for (int a = 0; a < 8; ++a) acc[a] += xs[a][i] * w;
    }
    for (int a = 0; a < 8; ++a) AV[(size_t)(g0 + a) * FP + t] = acc[a];
}

// ---------------- mol attention + mol GRU ----------------
__global__ __launch_bounds__(256) void k_mol_step(int step,
        const float* __restrict__ act,
        const float* __restrict__ AV,
        float* __restrict__ molF,
        const float* __restrict__ mask,
        const float* __restrict__ mAw, const float* __restrict__ mAb,
        const float* __restrict__ MihT, const float* __restrict__ MhhT,
        const float* __restrict__ mbih, const float* __restrict__ mbhh,
        float* __restrict__ o_mfv, float* __restrict__ o_unb,
        float* __restrict__ o_mawv, float* __restrict__ o_molfeat) {
    int b = blockIdx.x, t = threadIdx.x;
    int wave = t >> 6, lane = t & 63;
    __shared__ float am[FP], hh[FP], cx[FP];
    __shared__ float S2[LL], mw[LL];
    __shared__ float red[4];

    float hprev = molF[b * FP + t];
    hh[t] = hprev;
    am[t] = fmaxf(hprev, 0.f);
    __syncthreads();

    float v = am[t] * mAw[t];
#pragma unroll
    for (int off = 32; off >= 1; off >>= 1) v += __shfl_xor(v, off);
    if (lane == 0) red[wave] = v;
    __syncthreads();
    float s_self = red[0] + red[1] + red[2] + red[3];

    for (int l = wave; l < LL; l += 4) {
        float v2 = 0.f;
#pragma unroll
        for (int q = 0; q < 4; ++q) {
            int i = lane + 64 * q;
            v2 += act[((size_t)b * LL + l) * FP + i] * mAw[FP + i];
        }
#pragma unroll
        for (int off = 32; off >= 1; off >>= 1) v2 += __shfl_xor(v2, off);
        if (lane == 0) S2[l] = v2;
    }
    __syncthreads();

    if (t < LL) {
        float s = fmaxf(s_self + S2[t] + mAb[0], 0.f);
        if (mask[b * LL + t] == 0.f) s += -9e8f;
        S2[t] = s;
    }
    __syncthreads();

    float m = -1e30f;
    for (int l = 0; l < LL; ++l) m = fmaxf(m, S2[l]);
    float den = 0.f;
    for (int l = 0; l < LL; ++l) den += expf(S2[l] - m);
    if (t < LL) {
        float w = expf(S2[t] - m) / den * mask[b * LL + t];
        mw[t] = w;
        o_mawv[(size_t)step * (BB * LL) + b * LL + t] = w;
    }
    __syncthreads();

    float acc = 0.f;
    for (int l = 0; l < LL; ++l) acc += mw[l] * AV[((size_t)b * LL + l) * FP + t];
    cx[t] = fmaxf(acc, 0.f);
    __syncthreads();

    float air = mbih[t], aiz = mbih[FP + t], ain = mbih[2 * FP + t];
    float ahr = mbhh[t], ahz = mbhh[FP + t], ahn = mbhh[2 * FP + t];
    for (int i = 0; i < FP; ++i) {
        float c = cx[i], h = hh[i];
        air += c * MihT[i * 768 + t];
        aiz += c * MihT[i * 768 + FP + t];
        ain += c * MihT[i * 768 + 2 * FP + t];
        ahr += h * MhhT[i * 768 + t];
        ahz += h * MhhT[i * 768 + FP + t];
        ahn += h * MhhT[i * 768 + 2 * FP + t];
    }
    float r = 1.f / (1.f + expf(-(air + ahr)));
    float z = 1.f / (1.f + expf(-(aiz + ahz)));
    float n = tanhf(ain + r * ahn);
    float hn = (1.f - z) * n + z * hprev;

    molF[b * FP + t] = hn;
    o_unb[(size_t)(step + 1) * (BB * FP) + b * FP + t] = hn;
    o_mfv[(size_t)(step + 1) * (BB * FP) + b * FP + t] = fmaxf(hn, 0.f);
    if (step == TT - 1) o_molfeat[b * FP + t] = hn;
}

extern "C" void kernel_launch(void* const* d_in, const int* in_sizes, int n_in,
                              void* d_out, int out_size, void* d_ws, size_t ws_size,
                              hipStream_t stream) {
    const float* atom_list = (const float*)d_in[0];
    const float* bond_list = (const float*)d_in[1];
    const int*   adeg      = (const int*)d_in[2];
    const int*   bdeg      = (const int*)d_in[3];
    const float* amask     = (const float*)d_in[4];
    const float* atom_fc_W = (const float*)d_in[5];
    const float* atom_fc_b = (const float*)d_in[6];
    const float* nfc_W     = (const float*)d_in[7];
    const float* nfc_b     = (const float*)d_in[8];
    const float* gwih      = (const float*)d_in[9];
    const float* gwhh      = (const float*)d_in[10];
    const float* gbih      = (const float*)d_in[11];
    const float* gbhh      = (const float*)d_in[12];
    const float* alW       = (const float*)d_in[13];
    const float* alb       = (const float*)d_in[14];
    const float* atW       = (const float*)d_in[15];
    const float* atb       = (const float*)d_in[16];
    const float* mgwih     = (const float*)d_in[17];
    const float* mgwhh     = (const float*)d_in[18];
    const float* mgbih     = (const float*)d_in[19];
    const float* mgbhh     = (const float*)d_in[20];
    const float* malW      = (const float*)d_in[21];
    const float* malb      = (const float*)d_in[22];
    const float* matW      = (const float*)d_in[23];
    const float* matb      = (const float*)d_in[24];

    const size_t BLF = (size_t)BB * LL * FP;
    float* out = (float*)d_out;
    float* O0 = out;                                 // atom_feature / h (fp32)
    float* O1 = out + BLF;                           // afv (4,B,L,FP)
    float* O2 = O1 + 4 * BLF;                        // awv (3,B,L,K)
    float* O3 = O2 + (size_t)RR * BB * LL * KK;      // mfv
    float* O4 = O3 + (size_t)(TT + 1) * BB * FP;     // mol_unb
    float* O5 = O4 + (size_t)(TT + 1) * BB * FP;     // mawv
    float* O6 = O5 + (size_t)TT * BB * LL;           // mol_feature

    // ws layout
    float* ws = (float*)d_ws;
    short* XB   = (short*)ws;                        // BLF shorts: wn bf16
    short* XB2  = XB + BLF;                          // BLF shorts: ctx bf16
    short* HBb  = XB + 2 * BLF;                      // BLF shorts: h bf16
    short* ACTB = XB + 3 * BLF;                      // BLF shorts: relu(h) bf16
    float* AV   = ws;                                // BLF floats, aliases XB+XB2 (mol phase)
    float* rest = ws + 2 * BLF;
    short* ApreB = (short*)rest;                     // BLF shorts
    float* SW    = rest + BLF / 2;                   // B*L floats
    float* MOLF  = SW + (size_t)BB * LL;
    float* WafcT = MOLF + (size_t)BB * FP;
    float* WnT   = WafcT + AA * FP;
    float* MWaT  = WnT + (AA + BDD) * FP;
    float* MihT  = MWaT + (size_t)FP * FP;
    float* MhhT  = MihT + (size_t)FP * 768;
    short* GW    = (short*)(MhhT + (size_t)FP * 768);   // RR*2*(8*48*512) shorts
    short* WaF   = GW + (size_t)RR * 2 * 8 * 48 * 512;  // RR*(8*16*512) shorts
    (void)ws_size; (void)in_sizes; (void)n_in; (void)out_size;

    auto tr = [&](const float* src, float* dst, int O, int I) {
        int n = O * I;
        k_transpose<<<(n + 255) / 256, 256, 0, stream>>>(src, dst, O, I);
    };
    tr(atom_fc_W, WafcT, FP, AA);
    tr(nfc_W, WnT, FP, AA + BDD);
    tr(matW, MWaT, FP, FP);
    tr(mgwih, MihT, 768, FP);
    tr(mgwhh, MhhT, 768, FP);

    {
        int n = RR * 2 * 8 * 48 * 512;
        k_prep_gruw<<<(n + 255) / 256, 256, 0, stream>>>(gwih, gwhh, GW);
        int n2 = RR * 8 * 16 * 512;
        k_prep_waf<<<(n2 + 255) / 256, 256, 0, stream>>>(atW, WaF);
    }

    k_atom_fc8<<<BB * LL / 8, 256, 0, stream>>>(atom_list, WafcT, atom_fc_b, O1, O0, HBb);
    k_apre<<<BB * LL / 8, 256, 0, stream>>>(atom_list, WnT, nfc_b, ApreB);

    const size_t wblk = (size_t)8 * 48 * 512;
    const size_t ablk = (size_t)8 * 16 * 512;
    for (int d = 0; d < RR; ++d) {
        const short* selfB = (d == 0) ? HBb : ACTB;
        if (d == 0) {
            k_awn2<1><<<BB * 2, 512, 0, stream>>>(selfB, ApreB, bond_list, adeg, bdeg,
                    WnT, alW, alb, XB, SW, O2);
        } else {
            k_awn2<0><<<BB * 2, 512, 0, stream>>>(selfB, ACTB, bond_list, adeg, bdeg,
                    WnT, alW + (size_t)d * 2 * FP, alb + d,
                    XB, SW, O2 + (size_t)d * BB * LL * KK);
        }
        k_ctx_mfma<<<BB * LL / 32, 512, 0, stream>>>(XB, SW, WaF + (size_t)d * ablk,
                atb + (size_t)d * FP, XB2);
        if (d == RR - 1) {
            k_gru_mfma<1><<<BB * LL / 128, 512, 0, stream>>>(XB2, HBb, O0,
                    GW + (size_t)(d * 2 + 0) * wblk, GW + (size_t)(d * 2 + 1) * wblk,
                    gbih + (size_t)d * 768, gbhh + (size_t)d * 768,
                    O1 + (size_t)(d + 1) * BLF, HBb, ACTB);
        } else {
            k_gru_mfma<0><<<BB * LL / 128, 512, 0, stream>>>(XB2, HBb, O0,
                    GW + (size_t)(d * 2 + 0) * wblk, GW + (size_t)(d * 2 + 1) * wblk,
                    gbih + (size_t)d * 768, gbhh + (size_t)d * 768,
                    O1 + (size_t)(d + 1) * BLF, HBb, ACTB);
        }
    }

    const float* actFin = O1 + (size_t)RR * BLF;
    k_mol_reduce<<<BB, 256, 0, stream>>>(O0, actFin, amask, O4, O3, MOLF);
    k_av<<<BB * LL / 8, 256, 0, stream>>>(actFin, MWaT, matb, AV);
    for (int st = 0; st < TT; ++st) {
        k_mol_step<<<BB, 256, 0, stream>>>(st, actFin, AV, MOLF, amask,
                malW, malb, MihT, MhhT, mgbih, mgbhh,
                O3, O4, O5, O6);
    }
}

// Round 7
// 888.708 us; speedup vs baseline: 1.1768x; 1.1768x over previous
//
#include <hip/hip_runtime.h>
#include <hip/hip_bf16.h>

// Dims
#define BB 256
#define LL 128
#define AA 39
#define BDD 10
#define KK 6
#define MM 256
#define FP 256
#define RR 3
#define TT 2

using short8  = __attribute__((ext_vector_type(8))) short;
using short4v = __attribute__((ext_vector_type(4))) short;
using f32x4   = __attribute__((ext_vector_type(4))) float;
using f32x2   = __attribute__((ext_vector_type(2))) float;

__device__ __forceinline__ short f2bf(float f) {
    union { float f; unsigned u; } v; v.f = f;
    unsigned u = v.u;
    u += 0x7fffu + ((u >> 16) & 1u);   // round-to-nearest-even
    return (short)(u >> 16);
}
__device__ __forceinline__ float bf2f(short s) {
    union { unsigned u; float f; } v; v.u = ((unsigned)(unsigned short)s) << 16;
    return v.f;
}
__device__ __forceinline__ float wred64(float v) {
#pragma unroll
    for (int off = 32; off >= 1; off >>= 1) v += __shfl_xor(v, off);
    return v;
}

// ---------------- transpose: dst[i*O+o] = src[o*I+i] ----------------
__global__ __launch_bounds__(256) void k_transpose(const float* __restrict__ src,
                                                   float* __restrict__ dst, int O, int I) {
    int idx = blockIdx.x * 256 + threadIdx.x;
    if (idx >= O * I) return;
    int o = idx / I, i = idx - o * I;
    dst[i * O + o] = src[idx];
}

// ---------------- pack ALL GRU weights into MFMA fragment-major bf16 ----------------
// out layout: [d][mat][ks(8)][nt(48)][lane(64)][j(8)]
__global__ __launch_bounds__(256) void k_prep_gruw(const float* __restrict__ gwih,
                                                   const float* __restrict__ gwhh,
                                                   short* __restrict__ out) {
    int idx = blockIdx.x * 256 + threadIdx.x;
    if (idx >= RR * 2 * 8 * 48 * 512) return;
    int j = idx & 7;
    int lane = (idx >> 3) & 63;
    int blk = idx >> 9;
    int nt = blk % 48;
    int ks = (blk / 48) % 8;
    int mat = (blk / (48 * 8)) % 2;
    int d = blk / (48 * 8 * 2);
    int n = nt * 16 + (lane & 15);
    int k = ks * 32 + (lane >> 4) * 8 + j;
    const float* W = mat ? gwhh : gwih;
    out[idx] = f2bf(W[((size_t)d * 768 + n) * FP + k]);
}

// ---------------- pack ALL attend weights: [d][ks(8)][nt(16)][lane][j] ----------------
__global__ __launch_bounds__(256) void k_prep_waf(const float* __restrict__ atW,
                                                  short* __restrict__ out) {
    int idx = blockIdx.x * 256 + threadIdx.x;
    if (idx >= RR * 8 * 16 * 512) return;
    int j = idx & 7;
    int lane = (idx >> 3) & 63;
    int blk = idx >> 9;
    int nt = blk % 16;
    int ks = (blk / 16) % 8;
    int d = blk / 128;
    int n = nt * 16 + (lane & 15);
    int k = ks * 32 + (lane >> 4) * 8 + j;
    out[idx] = f2bf(atW[(size_t)d * FP * FP + (size_t)n * FP + k]);
}

// ---------------- atom fc (8 atoms/block) ----------------
__global__ __launch_bounds__(256) void k_atom_fc8(const float* __restrict__ atom_list,
                                                  const float* __restrict__ WafcT,
                                                  const float* __restrict__ bias,
                                                  float* __restrict__ out_pre,
                                                  float* __restrict__ hbuf,
                                                  short* __restrict__ hb16) {
    int g0 = blockIdx.x * 8;
    int t = threadIdx.x;
    __shared__ float x[8][AA];
    for (int i = t; i < 8 * AA; i += 256) x[i / AA][i % AA] = atom_list[(size_t)g0 * AA + i];
    __syncthreads();
    float acc[8];
    float bv = bias[t];
#pragma unroll
    for (int a = 0; a < 8; ++a) acc[a] = bv;
    for (int i = 0; i < AA; ++i) {
        float w = WafcT[i * FP + t];
#pragma unroll
        for (int a = 0; a < 8; ++a) acc[a] += x[a][i] * w;
    }
#pragma unroll
    for (int a = 0; a < 8; ++a) {
        size_t idx = (size_t)(g0 + a) * FP + t;
        out_pre[idx] = acc[a];
        float rl = fmaxf(acc[a], 0.f);
        hbuf[idx] = rl;
        hb16[idx] = f2bf(rl);   // h0 = relu(pre); also ACT source for d=0
    }
}

// ---------------- ApreB = bf16(atom_list @ WnA^T + bn) ----------------
__global__ __launch_bounds__(256) void k_apre(const float* __restrict__ atom_list,
                                              const float* __restrict__ WnT,
                                              const float* __restrict__ bn,
                                              short* __restrict__ ApreB) {
    int g0 = blockIdx.x * 8;
    int t = threadIdx.x;
    __shared__ float x[8][AA];
    for (int i = t; i < 8 * AA; i += 256) x[i / AA][i % AA] = atom_list[(size_t)g0 * AA + i];
    __syncthreads();
    float acc[8];
    float bv = bn[t];
#pragma unroll
    for (int a = 0; a < 8; ++a) acc[a] = bv;
    for (int i = 0; i < AA; ++i) {
        float w = WnT[i * FP + t];
#pragma unroll
        for (int a = 0; a < 8; ++a) acc[a] += x[a][i] * w;
    }
#pragma unroll
    for (int a = 0; a < 8; ++a) ApreB[(size_t)(g0 + a) * FP + t] = f2bf(acc[a]);
}

// ---------------- attention: per-molecule LDS-staged gather ----------------
// 2 blocks / molecule (512 thr each, 8 waves x 8 atoms); full 64KB slab staged.
template<int IS_D0>
__global__ __launch_bounds__(512) void k_awn2(
        const short* __restrict__ ACTB,     // relu'd act bf16 (self dots)
        const short* __restrict__ SRC,      // neighbor source to stage
        const float* __restrict__ bond_list,
        const int* __restrict__ adeg, const int* __restrict__ bdeg,
        const float* __restrict__ WnT,      // bond rows AA..AA+BDD-1 (d0 only)
        const float* __restrict__ alignW, const float* __restrict__ alignBp,
        short* __restrict__ wn_out, float* __restrict__ sw_out,
        float* __restrict__ awv_out) {
    __shared__ short snb[LL * FP];          // 64 KB
    const int b = blockIdx.x >> 1;
    const int half = blockIdx.x & 1;
    const int t = threadIdx.x;
    const int wave = t >> 6, lane = t & 63;

    // stage whole molecule slab (64KB) via global_load_lds width-16
    {
        const char* src = (const char*)(SRC + (size_t)b * LL * FP);
#pragma unroll
        for (int it = 0; it < 8; ++it) {
            int off = it * 8192 + wave * 1024 + lane * 16;
            __builtin_amdgcn_global_load_lds(
                (const __attribute__((address_space(1))) void*)(src + off),
                (__attribute__((address_space(3))) void*)((char*)snb + it * 8192 + wave * 1024),
                16, 0, 0);
        }
    }

    f32x4 w0 = *(const f32x4*)(alignW + lane * 4);
    f32x4 w1 = *(const f32x4*)(alignW + FP + lane * 4);
    float bias = alignBp[0];

    float wnt[IS_D0 ? BDD : 1][4];
    if constexpr (IS_D0) {
#pragma unroll
        for (int i = 0; i < BDD; ++i) {
            f32x4 v = *(const f32x4*)(WnT + (AA + i) * FP + lane * 4);
#pragma unroll
            for (int q = 0; q < 4; ++q) wnt[i][q] = v[q];
        }
    }

    __syncthreads();   // staging complete

#pragma unroll
    for (int ai = 0; ai < 8; ++ai) {
        const int al = half * 64 + wave * 8 + ai;
        const int ga = b * LL + al;

        short4v sv = *(const short4v*)(ACTB + (size_t)ga * FP + lane * 4);
        float ss = wred64(bf2f(sv[0]) * w0[0] + bf2f(sv[1]) * w0[1] +
                          bf2f(sv[2]) * w0[2] + bf2f(sv[3]) * w0[3]);

        int jx[KK];
#pragma unroll
        for (int k = 0; k < KK; ++k) jx[k] = adeg[ga * KK + k];

        float nf[KK][4];
        float sc[KK];
#pragma unroll
        for (int k = 0; k < KK; ++k) {
            short4v nv = *(const short4v*)(snb + jx[k] * FP + lane * 4);
            float f0 = bf2f(nv[0]), f1 = bf2f(nv[1]), f2 = bf2f(nv[2]), f3 = bf2f(nv[3]);
            if constexpr (IS_D0) {
                int bi = bdeg[ga * KK + k];
                const float* bp = bond_list + ((size_t)b * MM + bi) * BDD;
                float bb[BDD];
#pragma unroll
                for (int i = 0; i < 5; ++i) {
                    f32x2 v2 = *(const f32x2*)(bp + 2 * i);
                    bb[2 * i] = v2[0]; bb[2 * i + 1] = v2[1];
                }
                float b0 = 0.f, b1 = 0.f, b2 = 0.f, b3 = 0.f;
#pragma unroll
                for (int i = 0; i < BDD; ++i) {
                    b0 += bb[i] * wnt[i][0]; b1 += bb[i] * wnt[i][1];
                    b2 += bb[i] * wnt[i][2]; b3 += bb[i] * wnt[i][3];
                }
                f0 = fmaxf(f0 + b0, 0.f); f1 = fmaxf(f1 + b1, 0.f);
                f2 = fmaxf(f2 + b2, 0.f); f3 = fmaxf(f3 + b3, 0.f);
            }
            nf[k][0] = f0; nf[k][1] = f1; nf[k][2] = f2; nf[k][3] = f3;
            float s2 = wred64(f0 * w1[0] + f1 * w1[1] + f2 * w1[2] + f3 * w1[3]);
            float s = fmaxf(ss + s2 + bias, 0.f);
            if (jx[k] == LL - 1) s -= 9.0f;
            sc[k] = s;
        }

        float m = sc[0];
#pragma unroll
        for (int k = 1; k < KK; ++k) m = fmaxf(m, sc[k]);
        float e[KK], den = 0.f;
#pragma unroll
        for (int k = 0; k < KK; ++k) { e[k] = expf(sc[k] - m); den += e[k]; }
        float aw[KK], sumaw = 0.f;
#pragma unroll
        for (int k = 0; k < KK; ++k) {
            aw[k] = (jx[k] == LL - 1) ? 0.f : e[k] / den;
            sumaw += aw[k];
        }
        if (lane < KK) {
            float av = aw[0];
#pragma unroll
            for (int k = 1; k < KK; ++k) if (lane == k) av = aw[k];
            awv_out[(size_t)ga * KK + lane] = av;
        }
        if (lane == 0) sw_out[ga] = sumaw;

        short4v wo;
#pragma unroll
        for (int q = 0; q < 4; ++q) {
            float w = 0.f;
#pragma unroll
            for (int k = 0; k < KK; ++k) w += aw[k] * nf[k][q];
            wo[q] = f2bf(w);
        }
        *(short4v*)(wn_out + (size_t)ga * FP + lane * 4) = wo;
    }
}

// ---------------- ctx = relu(WN @ Wa^T + sumaw*ab), LDS-staged B, ks-stagger ----
__global__ __launch_bounds__(512) void k_ctx_mfma(
        const short* __restrict__ XB,      // wn bf16
        const float* __restrict__ SW,
        const short* __restrict__ WaF,     // frag-major (8,16,64,8)
        const float* __restrict__ ab,
        short* __restrict__ ctx_out) {
    __shared__ short lds[2][8192];         // 2 x 16KB
    const int t = threadIdx.x;
    const int wave = t >> 6, lane = t & 63;
    const int abase = blockIdx.x * 32 + (wave >> 2) * 16;
    const int wn4 = wave & 3;
    const int lr = lane & 15, lk = lane >> 4;
    const int kofs = blockIdx.x & 7;

#define CSTAGE(i) do { \
        int ke_ = ((i) + kofs) & 7; \
        _Pragma("unroll") \
        for (int e = 0; e < 2; ++e) { \
            int f = wave * 2 + e; \
            __builtin_amdgcn_global_load_lds( \
                (const __attribute__((address_space(1))) void*)(WaF + (size_t)(ke_ * 16 + f) * 512 + lane * 8), \
                (__attribute__((address_space(3))) void*)(&lds[(i) & 1][f * 512]), 16, 0, 0); \
        } } while (0)

    f32x4 acc[4] = {};
    const short8* xrow = (const short8*)(XB + (size_t)(abase + lr) * FP);

    CSTAGE(0);
#pragma unroll
    for (int i = 0; i < 8; ++i) {
        int ke = (i + kofs) & 7;
        short8 ax = xrow[ke * 4 + lk];
        __syncthreads();
        if (i < 7) CSTAGE(i + 1);
#pragma unroll
        for (int sub = 0; sub < 4; ++sub) {
            int nt = wn4 * 4 + sub;
            short8 bf = *(const short8*)(&lds[i & 1][nt * 512 + lane * 8]);
            acc[sub] = __builtin_amdgcn_mfma_f32_16x16x32_bf16(ax, bf, acc[sub], 0, 0, 0);
        }
    }
#undef CSTAGE

#pragma unroll
    for (int sub = 0; sub < 4; ++sub) {
        int c = wn4 * 64 + sub * 16 + lr;
        float abc = ab[c];
#pragma unroll
        for (int q = 0; q < 4; ++q) {
            int atom = abase + lk * 4 + q;
            float v = acc[sub][q] + SW[atom] * abc;
            ctx_out[(size_t)atom * FP + c] = f2bf(fmaxf(v, 0.f));
        }
    }
}

// ---------------- fused MFMA GRU: single pass, 24KB half-phase dbuf, 2 blk/CU ----
// 1024 blocks x 512 thr x 32 atoms. Each weight fragment staged ONCE per block.
// 32 phases: ks=((p>>2)+kofs)&7, mat=(p>>1)&1, half=p&1; 24 frags (24KB) per phase.
// LDS 48KB + VGPR<=128 (launch_bounds min-waves=4) => 2 blocks/CU, cross-block
// overlap hides the per-phase vmcnt drain at the barrier.
template<int LAST>
__global__ __launch_bounds__(512, 4) void k_gru_mfma(
        const short* __restrict__ XB,     // ctx bf16
        const short* __restrict__ HBl,    // h bf16 (read)
        float* __restrict__ hbuf,         // h fp32 (read old, write new)
        const short* __restrict__ Bih,    // frag-major (8,48,64,8)
        const short* __restrict__ Bhh,
        const float* __restrict__ bih, const float* __restrict__ bhh,
        float* __restrict__ act_out,
        short* __restrict__ HB_out,
        short* __restrict__ ACT_out) {
    __shared__ short lds[2][12288];       // 2 x 24KB
    const int t = threadIdx.x;
    const int wave = t >> 6, lane = t & 63;
    const int wn = wave & 3;
    const int lr = lane & 15, lk = lane >> 4;
    const int bid = blockIdx.x;
    const int kofs = bid & 7;
    const int abase = bid * 32 + (wave >> 2) * 16;

#define PKS(p)  ((((p) >> 2) + kofs) & 7)
#define STAGEP(p) do { \
        const short* base_ = ((((p) >> 1) & 1) ? Bhh : Bih) + (size_t)PKS(p) * 24576; \
        const int h_ = (p) & 1; \
        _Pragma("unroll") \
        for (int e = 0; e < 3; ++e) { \
            int j = wave * 3 + e; \
            int nt = 4 * (j >> 1) + 2 * h_ + (j & 1); \
            __builtin_amdgcn_global_load_lds( \
                (const __attribute__((address_space(1))) void*)(base_ + nt * 512 + lane * 8), \
                (__attribute__((address_space(3))) void*)(&lds[(p) & 1][j * 512]), 16, 0, 0); \
        } } while (0)

    const short8* xrow = (const short8*)(XB + (size_t)(abase + lr) * FP);
    const short8* hrow = (const short8*)(HBl + (size_t)(abase + lr) * FP);
    f32x4 acc_i[12] = {};
    f32x4 acc_h[12] = {};

    STAGEP(0);
    short8 ax{}, ah{};
#pragma unroll
    for (int p = 0; p < 32; ++p) {
        const int h_ = p & 1;
        if ((p & 3) == 0) {
            int ke = PKS(p);
            ax = xrow[ke * 4 + lk];
            ah = hrow[ke * 4 + lk];
        }
        __syncthreads();          // lds[p&1] staged; prev reads of lds[(p+1)&1] done
        if (p < 31) STAGEP(p + 1);
        const short8 a8 = ((p >> 1) & 1) ? ah : ax;
#pragma unroll
        for (int g = 0; g < 3; ++g) {
#pragma unroll
            for (int s2 = 0; s2 < 2; ++s2) {
                const int sub = 2 * h_ + s2;
                const int j = ((4 * g + wn) << 1) | s2;
                short8 bf = *(const short8*)(&lds[p & 1][j * 512 + lane * 8]);
                if ((p >> 1) & 1)
                    acc_h[g * 4 + sub] = __builtin_amdgcn_mfma_f32_16x16x32_bf16(a8, bf, acc_h[g * 4 + sub], 0, 0, 0);
                else
                    acc_i[g * 4 + sub] = __builtin_amdgcn_mfma_f32_16x16x32_bf16(a8, bf, acc_i[g * 4 + sub], 0, 0, 0);
            }
        }
    }
    __syncthreads();   // all HBl reads done before HB_out writes
#undef STAGEP
#undef PKS

#pragma unroll
    for (int sub = 0; sub < 4; ++sub) {
        int c = wn * 64 + sub * 16 + lr;
        float bir = bih[c], biz = bih[FP + c], bin_ = bih[2 * FP + c];
        float bhr = bhh[c], bhz = bhh[FP + c], bhn = bhh[2 * FP + c];
#pragma unroll
        for (int q = 0; q < 4; ++q) {
            int atom = abase + lk * 4 + q;
            size_t idx = (size_t)atom * FP + c;
            float hold = hbuf[idx];
            float r = 1.f / (1.f + expf(-(acc_i[0 * 4 + sub][q] + bir + acc_h[0 * 4 + sub][q] + bhr)));
            float z = 1.f / (1.f + expf(-(acc_i[1 * 4 + sub][q] + biz + acc_h[1 * 4 + sub][q] + bhz)));
            float n = tanhf(acc_i[2 * 4 + sub][q] + bin_ + r * (acc_h[2 * 4 + sub][q] + bhn));
            float hn = (1.f - z) * n + z * hold;
            float rl = fmaxf(hn, 0.f);
            hbuf[idx] = hn;
            act_out[idx] = rl;
            if constexpr (!LAST) {
                HB_out[idx] = f2bf(hn);
                ACT_out[idx] = f2bf(rl);
            }
        }
    }
}

// ---------------- mol reductions ----------------
__global__ __launch_bounds__(256) void k_mol_reduce(const float* __restrict__ hbuf,
                                                    const float* __restrict__ act,
                                                    const float* __restrict__ mask,
                                                    float* __restrict__ o_unb0,
                                                    float* __restrict__ o_mfv0,
                                                    float* __restrict__ molF) {
    int b = blockIdx.x, t = threadIdx.x;
    float s1 = 0.f, s2 = 0.f;
    for (int l = 0; l < LL; ++l) {
        float mk = mask[b * LL + l];
        s1 += hbuf[((size_t)b * LL + l) * FP + t] * mk;
        s2 += act[((size_t)b * LL + l) * FP + t] * mk;
    }
    o_unb0[b * FP + t] = s1;
    o_mfv0[b * FP + t] = s2;
    molF[b * FP + t] = s2;
}

// ---------------- AV = act @ mol_attend_W.T + b ----------------
__global__ __launch_bounds__(256) void k_av(const float* __restrict__ act,
                                            const float* __restrict__ MWaT,
                                            const float* __restrict__ mab,
                                            float* __restrict__ AV) {
    int g0 = blockIdx.x * 8;
    int t = threadIdx.x;
    __shared__ float xs[8][FP];
    for (int a = 0; a < 8; ++a) xs[a][t] = act[(size_t)(g0 + a) * FP + t];
    __syncthreads();
    float acc[8];
    float bb2 = mab[t];
#pragma unroll
    for (int a = 0; a < 8; ++a) acc[a] = bb2;
    for (int i = 0; i < FP; ++i) {
        float w = MWaT[i * FP + t];
#pragma unroll
        for (int a = 0; a < 8; ++a) acc[a] += xs[a][i] * w;
    }
    for (int a = 0; a < 8; ++a) AV[(size_t)(g0 + a) * FP + t] = acc[a];
}

// ---------------- mol attention + mol GRU ----------------
__global__ __launch_bounds__(256) void k_mol_step(int step,
        const float* __restrict__ act,
        const float* __restrict__ AV,
        float* __restrict__ molF,
        const float* __restrict__ mask,
        const float* __restrict__ mAw, const float* __restrict__ mAb,
        const float* __restrict__ MihT, const float* __restrict__ MhhT,
        const float* __restrict__ mbih, const float* __restrict__ mbhh,
        float* __restrict__ o_mfv, float* __restrict__ o_unb,
        float* __restrict__ o_mawv, float* __restrict__ o_molfeat) {
    int b = blockIdx.x, t = threadIdx.x;
    int wave = t >> 6, lane = t & 63;
    __shared__ float am[FP], hh[FP], cx[FP];
    __shared__ float S2[LL], mw[LL];
    __shared__ float red[4];

    float hprev = molF[b * FP + t];
    hh[t] = hprev;
    am[t] = fmaxf(hprev, 0.f);
    __syncthreads();

    float v = am[t] * mAw[t];
#pragma unroll
    for (int off = 32; off >= 1; off >>= 1) v += __shfl_xor(v, off);
    if (lane == 0) red[wave] = v;
    __syncthreads();
    float s_self = red[0] + red[1] + red[2] + red[3];

    for (int l = wave; l < LL; l += 4) {
        float v2 = 0.f;
#pragma unroll
        for (int q = 0; q < 4; ++q) {
            int i = lane + 64 * q;
            v2 += act[((size_t)b * LL + l) * FP + i] * mAw[FP + i];
        }
#pragma unroll
        for (int off = 32; off >= 1; off >>= 1) v2 += __shfl_xor(v2, off);
        if (lane == 0) S2[l] = v2;
    }
    __syncthreads();

    if (t < LL) {
        float s = fmaxf(s_self + S2[t] + mAb[0], 0.f);
        if (mask[b * LL + t] == 0.f) s += -9e8f;
        S2[t] = s;
    }
    __syncthreads();

    float m = -1e30f;
    for (int l = 0; l < LL; ++l) m = fmaxf(m, S2[l]);
    float den = 0.f;
    for (int l = 0; l < LL; ++l) den += expf(S2[l] - m);
    if (t < LL) {
        float w = expf(S2[t] - m) / den * mask[b * LL + t];
        mw[t] = w;
        o_mawv[(size_t)step * (BB * LL) + b * LL + t] = w;
    }
    __syncthreads();

    float acc = 0.f;
    for (int l = 0; l < LL; ++l) acc += mw[l] * AV[((size_t)b * LL + l) * FP + t];
    cx[t] = fmaxf(acc, 0.f);
    __syncthreads();

    float air = mbih[t], aiz = mbih[FP + t], ain = mbih[2 * FP + t];
    float ahr = mbhh[t], ahz = mbhh[FP + t], ahn = mbhh[2 * FP + t];
    for (int i = 0; i < FP; ++i) {
        float c = cx[i], h = hh[i];
        air += c * MihT[i * 768 + t];
        aiz += c * MihT[i * 768 + FP + t];
        ain += c * MihT[i * 768 + 2 * FP + t];
        ahr += h * MhhT[i * 768 + t];
        ahz += h * MhhT[i * 768 + FP + t];
        ahn += h * MhhT[i * 768 + 2 * FP + t];
    }
    float r = 1.f / (1.f + expf(-(air + ahr)));
    float z = 1.f / (1.f + expf(-(aiz + ahz)));
    float n = tanhf(ain + r * ahn);
    float hn = (1.f - z) * n + z * hprev;

    molF[b * FP + t] = hn;
    o_unb[(size_t)(step + 1) * (BB * FP) + b * FP + t] = hn;
    o_mfv[(size_t)(step + 1) * (BB * FP) + b * FP + t] = fmaxf(hn, 0.f);
    if (step == TT - 1) o_molfeat[b * FP + t] = hn;
}

extern "C" void kernel_launch(void* const* d_in, const int* in_sizes, int n_in,
                              void* d_out, int out_size, void* d_ws, size_t ws_size,
                              hipStream_t stream) {
    const float* atom_list = (const float*)d_in[0];
    const float* bond_list = (const float*)d_in[1];
    const int*   adeg      = (const int*)d_in[2];
    const int*   bdeg      = (const int*)d_in[3];
    const float* amask     = (const float*)d_in[4];
    const float* atom_fc_W = (const float*)d_in[5];
    const float* atom_fc_b = (const float*)d_in[6];
    const float* nfc_W     = (const float*)d_in[7];
    const float* nfc_b     = (const float*)d_in[8];
    const float* gwih      = (const float*)d_in[9];
    const float* gwhh      = (const float*)d_in[10];
    const float* gbih      = (const float*)d_in[11];
    const float* gbhh      = (const float*)d_in[12];
    const float* alW       = (const float*)d_in[13];
    const float* alb       = (const float*)d_in[14];
    const float* atW       = (const float*)d_in[15];
    const float* atb       = (const float*)d_in[16];
    const float* mgwih     = (const float*)d_in[17];
    const float* mgwhh     = (const float*)d_in[18];
    const float* mgbih     = (const float*)d_in[19];
    const float* mgbhh     = (const float*)d_in[20];
    const float* malW      = (const float*)d_in[21];
    const float* malb      = (const float*)d_in[22];
    const float* matW      = (const float*)d_in[23];
    const float* matb      = (const float*)d_in[24];

    const size_t BLF = (size_t)BB * LL * FP;
    float* out = (float*)d_out;
    float* O0 = out;                                 // atom_feature / h (fp32)
    float* O1 = out + BLF;                           // afv (4,B,L,FP)
    float* O2 = O1 + 4 * BLF;                        // awv (3,B,L,K)
    float* O3 = O2 + (size_t)RR * BB * LL * KK;      // mfv
    float* O4 = O3 + (size_t)(TT + 1) * BB * FP;     // mol_unb
    float* O5 = O4 + (size_t)(TT + 1) * BB * FP;     // mawv
    float* O6 = O5 + (size_t)TT * BB * LL;           // mol_feature

    // ws layout
    float* ws = (float*)d_ws;
    short* XB   = (short*)ws;                        // BLF shorts: wn bf16
    short* XB2  = XB + BLF;                          // BLF shorts: ctx bf16
    short* HBb  = XB + 2 * BLF;                      // BLF shorts: h bf16
    short* ACTB = XB + 3 * BLF;                      // BLF shorts: relu(h) bf16
    float* AV   = ws;                                // BLF floats, aliases XB+XB2 (mol phase)
    float* rest = ws + 2 * BLF;
    short* ApreB = (short*)rest;                     // BLF shorts
    float* SW    = rest + BLF / 2;                   // B*L floats
    float* MOLF  = SW + (size_t)BB * LL;
    float* WafcT = MOLF + (size_t)BB * FP;
    float* WnT   = WafcT + AA * FP;
    float* MWaT  = WnT + (AA + BDD) * FP;
    float* MihT  = MWaT + (size_t)FP * FP;
    float* MhhT  = MihT + (size_t)FP * 768;
    short* GW    = (short*)(MhhT + (size_t)FP * 768);   // RR*2*(8*48*512) shorts
    short* WaF   = GW + (size_t)RR * 2 * 8 * 48 * 512;  // RR*(8*16*512) shorts
    (void)ws_size; (void)in_sizes; (void)n_in; (void)out_size;

    auto tr = [&](const float* src, float* dst, int O, int I) {
        int n = O * I;
        k_transpose<<<(n + 255) / 256, 256, 0, stream>>>(src, dst, O, I);
    };
    tr(atom_fc_W, WafcT, FP, AA);
    tr(nfc_W, WnT, FP, AA + BDD);
    tr(matW, MWaT, FP, FP);
    tr(mgwih, MihT, 768, FP);
    tr(mgwhh, MhhT, 768, FP);

    {
        int n = RR * 2 * 8 * 48 * 512;
        k_prep_gruw<<<(n + 255) / 256, 256, 0, stream>>>(gwih, gwhh, GW);
        int n2 = RR * 8 * 16 * 512;
        k_prep_waf<<<(n2 + 255) / 256, 256, 0, stream>>>(atW, WaF);
    }

    k_atom_fc8<<<BB * LL / 8, 256, 0, stream>>>(atom_list, WafcT, atom_fc_b, O1, O0, HBb);
    k_apre<<<BB * LL / 8, 256, 0, stream>>>(atom_list, WnT, nfc_b, ApreB);

    const size_t wblk = (size_t)8 * 48 * 512;
    const size_t ablk = (size_t)8 * 16 * 512;
    for (int d = 0; d < RR; ++d) {
        const short* selfB = (d == 0) ? HBb : ACTB;
        if (d == 0) {
            k_awn2<1><<<BB * 2, 512, 0, stream>>>(selfB, ApreB, bond_list, adeg, bdeg,
                    WnT, alW, alb, XB, SW, O2);
        } else {
            k_awn2<0><<<BB * 2, 512, 0, stream>>>(selfB, ACTB, bond_list, adeg, bdeg,
                    WnT, alW + (size_t)d * 2 * FP, alb + d,
                    XB, SW, O2 + (size_t)d * BB * LL * KK);
        }
        k_ctx_mfma<<<BB * LL / 32, 512, 0, stream>>>(XB, SW, WaF + (size_t)d * ablk,
                atb + (size_t)d * FP, XB2);
        if (d == RR - 1) {
            k_gru_mfma<1><<<BB * LL / 32, 512, 0, stream>>>(XB2, HBb, O0,
                    GW + (size_t)(d * 2 + 0) * wblk, GW + (size_t)(d * 2 + 1) * wblk,
                    gbih + (size_t)d * 768, gbhh + (size_t)d * 768,
                    O1 + (size_t)(d + 1) * BLF, HBb, ACTB);
        } else {
            k_gru_mfma<0><<<BB * LL / 32, 512, 0, stream>>>(XB2, HBb, O0,
                    GW + (size_t)(d * 2 + 0) * wblk, GW + (size_t)(d * 2 + 1) * wblk,
                    gbih + (size_t)d * 768, gbhh + (size_t)d * 768,
                    O1 + (size_t)(d + 1) * BLF, HBb, ACTB);
        }
    }

    const float* actFin = O1 + (size_t)RR * BLF;
    k_mol_reduce<<<BB, 256, 0, stream>>>(O0, actFin, amask, O4, O3, MOLF);
    k_av<<<BB * LL / 8, 256, 0, stream>>>(actFin, MWaT, matb, AV);
    for (int st = 0; st < TT; ++st) {
        k_mol_step<<<BB, 256, 0, stream>>>(st, actFin, AV, MOLF, amask,
                malW, malb, MihT, MhhT, mgbih, mgbhh,
                O3, O4, O5, O6);
    }
}

// Round 8
// 663.431 us; speedup vs baseline: 1.5764x; 1.3396x over previous
//
#include <hip/hip_runtime.h>
#include <hip/hip_bf16.h>

// Dims
#define BB 256
#define LL 128
#define AA 39
#define BDD 10
#define KK 6
#define MM 256
#define FP 256
#define RR 3
#define TT 2

using short8  = __attribute__((ext_vector_type(8))) short;
using short4v = __attribute__((ext_vector_type(4))) short;
using f32x4   = __attribute__((ext_vector_type(4))) float;
using f32x2   = __attribute__((ext_vector_type(2))) float;

__device__ __forceinline__ short f2bf(float f) {
    union { float f; unsigned u; } v; v.f = f;
    unsigned u = v.u;
    u += 0x7fffu + ((u >> 16) & 1u);   // round-to-nearest-even
    return (short)(u >> 16);
}
__device__ __forceinline__ float bf2f(short s) {
    union { unsigned u; float f; } v; v.u = ((unsigned)(unsigned short)s) << 16;
    return v.f;
}
__device__ __forceinline__ float wred64(float v) {
#pragma unroll
    for (int off = 32; off >= 1; off >>= 1) v += __shfl_xor(v, off);
    return v;
}

// ---------------- transpose: dst[i*O+o] = src[o*I+i] ----------------
__global__ __launch_bounds__(256) void k_transpose(const float* __restrict__ src,
                                                   float* __restrict__ dst, int O, int I) {
    int idx = blockIdx.x * 256 + threadIdx.x;
    if (idx >= O * I) return;
    int o = idx / I, i = idx - o * I;
    dst[i * O + o] = src[idx];
}

// ---------------- pack ALL GRU weights into MFMA fragment-major bf16 ----------------
// out layout: [d][mat][ks(8)][nt(48)][lane(64)][j(8)]
__global__ __launch_bounds__(256) void k_prep_gruw(const float* __restrict__ gwih,
                                                   const float* __restrict__ gwhh,
                                                   short* __restrict__ out) {
    int idx = blockIdx.x * 256 + threadIdx.x;
    if (idx >= RR * 2 * 8 * 48 * 512) return;
    int j = idx & 7;
    int lane = (idx >> 3) & 63;
    int blk = idx >> 9;
    int nt = blk % 48;
    int ks = (blk / 48) % 8;
    int mat = (blk / (48 * 8)) % 2;
    int d = blk / (48 * 8 * 2);
    int n = nt * 16 + (lane & 15);
    int k = ks * 32 + (lane >> 4) * 8 + j;
    const float* W = mat ? gwhh : gwih;
    out[idx] = f2bf(W[((size_t)d * 768 + n) * FP + k]);
}

// ---------------- pack ALL attend weights: [d][ks(8)][nt(16)][lane][j] ----------------
__global__ __launch_bounds__(256) void k_prep_waf(const float* __restrict__ atW,
                                                  short* __restrict__ out) {
    int idx = blockIdx.x * 256 + threadIdx.x;
    if (idx >= RR * 8 * 16 * 512) return;
    int j = idx & 7;
    int lane = (idx >> 3) & 63;
    int blk = idx >> 9;
    int nt = blk % 16;
    int ks = (blk / 16) % 8;
    int d = blk / 128;
    int n = nt * 16 + (lane & 15);
    int k = ks * 32 + (lane >> 4) * 8 + j;
    out[idx] = f2bf(atW[(size_t)d * FP * FP + (size_t)n * FP + k]);
}

// ---------------- atom fc (8 atoms/block) ----------------
__global__ __launch_bounds__(256) void k_atom_fc8(const float* __restrict__ atom_list,
                                                  const float* __restrict__ WafcT,
                                                  const float* __restrict__ bias,
                                                  float* __restrict__ out_pre,
                                                  float* __restrict__ hbuf,
                                                  short* __restrict__ hb16) {
    int g0 = blockIdx.x * 8;
    int t = threadIdx.x;
    __shared__ float x[8][AA];
    for (int i = t; i < 8 * AA; i += 256) x[i / AA][i % AA] = atom_list[(size_t)g0 * AA + i];
    __syncthreads();
    float acc[8];
    float bv = bias[t];
#pragma unroll
    for (int a = 0; a < 8; ++a) acc[a] = bv;
    for (int i = 0; i < AA; ++i) {
        float w = WafcT[i * FP + t];
#pragma unroll
        for (int a = 0; a < 8; ++a) acc[a] += x[a][i] * w;
    }
#pragma unroll
    for (int a = 0; a < 8; ++a) {
        size_t idx = (size_t)(g0 + a) * FP + t;
        out_pre[idx] = acc[a];
        float rl = fmaxf(acc[a], 0.f);
        hbuf[idx] = rl;
        hb16[idx] = f2bf(rl);   // h0 = relu(pre); also ACT source for d=0
    }
}

// ---------------- ApreB = bf16(atom_list @ WnA^T + bn) ----------------
__global__ __launch_bounds__(256) void k_apre(const float* __restrict__ atom_list,
                                              const float* __restrict__ WnT,
                                              const float* __restrict__ bn,
                                              short* __restrict__ ApreB) {
    int g0 = blockIdx.x * 8;
    int t = threadIdx.x;
    __shared__ float x[8][AA];
    for (int i = t; i < 8 * AA; i += 256) x[i / AA][i % AA] = atom_list[(size_t)g0 * AA + i];
    __syncthreads();
    float acc[8];
    float bv = bn[t];
#pragma unroll
    for (int a = 0; a < 8; ++a) acc[a] = bv;
    for (int i = 0; i < AA; ++i) {
        float w = WnT[i * FP + t];
#pragma unroll
        for (int a = 0; a < 8; ++a) acc[a] += x[a][i] * w;
    }
#pragma unroll
    for (int a = 0; a < 8; ++a) ApreB[(size_t)(g0 + a) * FP + t] = f2bf(acc[a]);
}

// ---------------- attention: per-molecule LDS-staged gather ----------------
// 2 blocks / molecule (512 thr each, 8 waves x 8 atoms); full 64KB slab staged.
template<int IS_D0>
__global__ __launch_bounds__(512) void k_awn2(
        const short* __restrict__ ACTB,     // relu'd act bf16 (self dots)
        const short* __restrict__ SRC,      // neighbor source to stage
        const float* __restrict__ bond_list,
        const int* __restrict__ adeg, const int* __restrict__ bdeg,
        const float* __restrict__ WnT,      // bond rows AA..AA+BDD-1 (d0 only)
        const float* __restrict__ alignW, const float* __restrict__ alignBp,
        short* __restrict__ wn_out, float* __restrict__ sw_out,
        float* __restrict__ awv_out) {
    __shared__ short snb[LL * FP];          // 64 KB
    const int b = blockIdx.x >> 1;
    const int half = blockIdx.x & 1;
    const int t = threadIdx.x;
    const int wave = t >> 6, lane = t & 63;

    // stage whole molecule slab (64KB) via global_load_lds width-16
    {
        const char* src = (const char*)(SRC + (size_t)b * LL * FP);
#pragma unroll
        for (int it = 0; it < 8; ++it) {
            int off = it * 8192 + wave * 1024 + lane * 16;
            __builtin_amdgcn_global_load_lds(
                (const __attribute__((address_space(1))) void*)(src + off),
                (__attribute__((address_space(3))) void*)((char*)snb + it * 8192 + wave * 1024),
                16, 0, 0);
        }
    }

    f32x4 w0 = *(const f32x4*)(alignW + lane * 4);
    f32x4 w1 = *(const f32x4*)(alignW + FP + lane * 4);
    float bias = alignBp[0];

    float wnt[IS_D0 ? BDD : 1][4];
    if constexpr (IS_D0) {
#pragma unroll
        for (int i = 0; i < BDD; ++i) {
            f32x4 v = *(const f32x4*)(WnT + (AA + i) * FP + lane * 4);
#pragma unroll
            for (int q = 0; q < 4; ++q) wnt[i][q] = v[q];
        }
    }

    __syncthreads();   // staging complete

#pragma unroll
    for (int ai = 0; ai < 8; ++ai) {
        const int al = half * 64 + wave * 8 + ai;
        const int ga = b * LL + al;

        short4v sv = *(const short4v*)(ACTB + (size_t)ga * FP + lane * 4);
        float ss = wred64(bf2f(sv[0]) * w0[0] + bf2f(sv[1]) * w0[1] +
                          bf2f(sv[2]) * w0[2] + bf2f(sv[3]) * w0[3]);

        int jx[KK];
#pragma unroll
        for (int k = 0; k < KK; ++k) jx[k] = adeg[ga * KK + k];

        float nf[KK][4];
        float sc[KK];
#pragma unroll
        for (int k = 0; k < KK; ++k) {
            short4v nv = *(const short4v*)(snb + jx[k] * FP + lane * 4);
            float f0 = bf2f(nv[0]), f1 = bf2f(nv[1]), f2 = bf2f(nv[2]), f3 = bf2f(nv[3]);
            if constexpr (IS_D0) {
                int bi = bdeg[ga * KK + k];
                const float* bp = bond_list + ((size_t)b * MM + bi) * BDD;
                float bb[BDD];
#pragma unroll
                for (int i = 0; i < 5; ++i) {
                    f32x2 v2 = *(const f32x2*)(bp + 2 * i);
                    bb[2 * i] = v2[0]; bb[2 * i + 1] = v2[1];
                }
                float b0 = 0.f, b1 = 0.f, b2 = 0.f, b3 = 0.f;
#pragma unroll
                for (int i = 0; i < BDD; ++i) {
                    b0 += bb[i] * wnt[i][0]; b1 += bb[i] * wnt[i][1];
                    b2 += bb[i] * wnt[i][2]; b3 += bb[i] * wnt[i][3];
                }
                f0 = fmaxf(f0 + b0, 0.f); f1 = fmaxf(f1 + b1, 0.f);
                f2 = fmaxf(f2 + b2, 0.f); f3 = fmaxf(f3 + b3, 0.f);
            }
            nf[k][0] = f0; nf[k][1] = f1; nf[k][2] = f2; nf[k][3] = f3;
            float s2 = wred64(f0 * w1[0] + f1 * w1[1] + f2 * w1[2] + f3 * w1[3]);
            float s = fmaxf(ss + s2 + bias, 0.f);
            if (jx[k] == LL - 1) s -= 9.0f;
            sc[k] = s;
        }

        float m = sc[0];
#pragma unroll
        for (int k = 1; k < KK; ++k) m = fmaxf(m, sc[k]);
        float e[KK], den = 0.f;
#pragma unroll
        for (int k = 0; k < KK; ++k) { e[k] = expf(sc[k] - m); den += e[k]; }
        float aw[KK], sumaw = 0.f;
#pragma unroll
        for (int k = 0; k < KK; ++k) {
            aw[k] = (jx[k] == LL - 1) ? 0.f : e[k] / den;
            sumaw += aw[k];
        }
        if (lane < KK) {
            float av = aw[0];
#pragma unroll
            for (int k = 1; k < KK; ++k) if (lane == k) av = aw[k];
            awv_out[(size_t)ga * KK + lane] = av;
        }
        if (lane == 0) sw_out[ga] = sumaw;

        short4v wo;
#pragma unroll
        for (int q = 0; q < 4; ++q) {
            float w = 0.f;
#pragma unroll
            for (int k = 0; k < KK; ++k) w += aw[k] * nf[k][q];
            wo[q] = f2bf(w);
        }
        *(short4v*)(wn_out + (size_t)ga * FP + lane * 4) = wo;
    }
}

// ---------------- ctx = relu(WN @ Wa^T + sumaw*ab), LDS-staged B, ks-stagger ----
__global__ __launch_bounds__(512) void k_ctx_mfma(
        const short* __restrict__ XB,      // wn bf16
        const float* __restrict__ SW,
        const short* __restrict__ WaF,     // frag-major (8,16,64,8)
        const float* __restrict__ ab,
        short* __restrict__ ctx_out) {
    __shared__ short lds[2][8192];         // 2 x 16KB
    const int t = threadIdx.x;
    const int wave = t >> 6, lane = t & 63;
    const int abase = blockIdx.x * 32 + (wave >> 2) * 16;
    const int wn4 = wave & 3;
    const int lr = lane & 15, lk = lane >> 4;
    const int kofs = blockIdx.x & 7;

#define CSTAGE(i) do { \
        int ke_ = ((i) + kofs) & 7; \
        _Pragma("unroll") \
        for (int e = 0; e < 2; ++e) { \
            int f = wave * 2 + e; \
            __builtin_amdgcn_global_load_lds( \
                (const __attribute__((address_space(1))) void*)(WaF + (size_t)(ke_ * 16 + f) * 512 + lane * 8), \
                (__attribute__((address_space(3))) void*)(&lds[(i) & 1][f * 512]), 16, 0, 0); \
        } } while (0)

    f32x4 acc[4] = {};
    const short8* xrow = (const short8*)(XB + (size_t)(abase + lr) * FP);

    CSTAGE(0);
#pragma unroll
    for (int i = 0; i < 8; ++i) {
        int ke = (i + kofs) & 7;
        short8 ax = xrow[ke * 4 + lk];
        __syncthreads();
        if (i < 7) CSTAGE(i + 1);
#pragma unroll
        for (int sub = 0; sub < 4; ++sub) {
            int nt = wn4 * 4 + sub;
            short8 bf = *(const short8*)(&lds[i & 1][nt * 512 + lane * 8]);
            acc[sub] = __builtin_amdgcn_mfma_f32_16x16x32_bf16(ax, bf, acc[sub], 0, 0, 0);
        }
    }
#undef CSTAGE

#pragma unroll
    for (int sub = 0; sub < 4; ++sub) {
        int c = wn4 * 64 + sub * 16 + lr;
        float abc = ab[c];
#pragma unroll
        for (int q = 0; q < 4; ++q) {
            int atom = abase + lk * 4 + q;
            float v = acc[sub][q] + SW[atom] * abc;
            ctx_out[(size_t)atom * FP + c] = f2bf(fmaxf(v, 0.f));
        }
    }
}

// ---------------- fused MFMA GRU: single pass, 24KB dbuf, fused r/z accumulators --
// 1024 blocks x 512 thr x 32 atoms; each weight fragment staged ONCE per block.
// r/z gates: ih and hh MFMAs share ONE accumulator (C-in accumulates) ->
// 16 f32x4 accumulators total (64 VGPR) -> fits 128-reg budget of 4 waves/EU,
// no spill; 48KB LDS -> 2 blocks/CU for cross-block latency hiding.
template<int LAST>
__global__ __launch_bounds__(512, 4) void k_gru_mfma(
        const short* __restrict__ XB,     // ctx bf16
        const short* __restrict__ HBl,    // h bf16 (read)
        float* __restrict__ hbuf,         // h fp32 (read old, write new)
        const short* __restrict__ Bih,    // frag-major (8,48,64,8)
        const short* __restrict__ Bhh,
        const float* __restrict__ bih, const float* __restrict__ bhh,
        float* __restrict__ act_out,
        short* __restrict__ HB_out,
        short* __restrict__ ACT_out) {
    __shared__ short lds[2][12288];       // 2 x 24KB
    const int t = threadIdx.x;
    const int wave = t >> 6, lane = t & 63;
    const int wn = wave & 3;
    const int lr = lane & 15, lk = lane >> 4;
    const int bid = blockIdx.x;
    const int kofs = bid & 7;
    const int abase = bid * 32 + (wave >> 2) * 16;

#define PKS(p)  ((((p) >> 2) + kofs) & 7)
#define STAGEP(p) do { \
        const short* base_ = ((((p) >> 1) & 1) ? Bhh : Bih) + (size_t)PKS(p) * 24576; \
        const int h_ = (p) & 1; \
        _Pragma("unroll") \
        for (int e = 0; e < 3; ++e) { \
            int j = wave * 3 + e; \
            int nt = 4 * (j >> 1) + 2 * h_ + (j & 1); \
            __builtin_amdgcn_global_load_lds( \
                (const __attribute__((address_space(1))) void*)(base_ + nt * 512 + lane * 8), \
                (__attribute__((address_space(3))) void*)(&lds[(p) & 1][j * 512]), 16, 0, 0); \
        } } while (0)

    const short8* xrow = (const short8*)(XB + (size_t)(abase + lr) * FP);
    const short8* hrow = (const short8*)(HBl + (size_t)(abase + lr) * FP);
    f32x4 acc_rz[8] = {};   // [g(2)*4 + sub]: gi+gh fused
    f32x4 acc_in[4] = {};   // i_n
    f32x4 acc_hn[4] = {};   // h_n

    STAGEP(0);
    short8 ax{}, ah{};
#pragma unroll
    for (int p = 0; p < 32; ++p) {
        const int h_ = p & 1;
        const int mat = (p >> 1) & 1;
        if ((p & 3) == 0) {
            int ke = PKS(p);
            ax = xrow[ke * 4 + lk];
            ah = hrow[ke * 4 + lk];
        }
        __syncthreads();          // lds[p&1] staged; prev reads of lds[(p+1)&1] done
        if (p < 31) STAGEP(p + 1);
        const short8 a8 = mat ? ah : ax;
#pragma unroll
        for (int g = 0; g < 3; ++g) {
#pragma unroll
            for (int s2 = 0; s2 < 2; ++s2) {
                const int sub = 2 * h_ + s2;
                const int j = ((4 * g + wn) << 1) | s2;
                short8 bf = *(const short8*)(&lds[p & 1][j * 512 + lane * 8]);
                if (g < 2)
                    acc_rz[g * 4 + sub] = __builtin_amdgcn_mfma_f32_16x16x32_bf16(a8, bf, acc_rz[g * 4 + sub], 0, 0, 0);
                else if (mat)
                    acc_hn[sub] = __builtin_amdgcn_mfma_f32_16x16x32_bf16(a8, bf, acc_hn[sub], 0, 0, 0);
                else
                    acc_in[sub] = __builtin_amdgcn_mfma_f32_16x16x32_bf16(a8, bf, acc_in[sub], 0, 0, 0);
            }
        }
    }
    __syncthreads();   // all HBl reads done before HB_out writes
#undef STAGEP
#undef PKS

#pragma unroll
    for (int sub = 0; sub < 4; ++sub) {
        int c = wn * 64 + sub * 16 + lr;
        float brz_r = bih[c] + bhh[c];
        float brz_z = bih[FP + c] + bhh[FP + c];
        float bin_ = bih[2 * FP + c];
        float bhn = bhh[2 * FP + c];
#pragma unroll
        for (int q = 0; q < 4; ++q) {
            int atom = abase + lk * 4 + q;
            size_t idx = (size_t)atom * FP + c;
            float hold = hbuf[idx];
            float r = 1.f / (1.f + expf(-(acc_rz[0 * 4 + sub][q] + brz_r)));
            float z = 1.f / (1.f + expf(-(acc_rz[1 * 4 + sub][q] + brz_z)));
            float n = tanhf(acc_in[sub][q] + bin_ + r * (acc_hn[sub][q] + bhn));
            float hn = (1.f - z) * n + z * hold;
            float rl = fmaxf(hn, 0.f);
            hbuf[idx] = hn;
            act_out[idx] = rl;
            if constexpr (!LAST) {
                HB_out[idx] = f2bf(hn);
                ACT_out[idx] = f2bf(rl);
            }
        }
    }
}

// ---------------- mol reductions ----------------
__global__ __launch_bounds__(256) void k_mol_reduce(const float* __restrict__ hbuf,
                                                    const float* __restrict__ act,
                                                    const float* __restrict__ mask,
                                                    float* __restrict__ o_unb0,
                                                    float* __restrict__ o_mfv0,
                                                    float* __restrict__ molF) {
    int b = blockIdx.x, t = threadIdx.x;
    float s1 = 0.f, s2 = 0.f;
    for (int l = 0; l < LL; ++l) {
        float mk = mask[b * LL + l];
        s1 += hbuf[((size_t)b * LL + l) * FP + t] * mk;
        s2 += act[((size_t)b * LL + l) * FP + t] * mk;
    }
    o_unb0[b * FP + t] = s1;
    o_mfv0[b * FP + t] = s2;
    molF[b * FP + t] = s2;
}

// ---------------- AV = act @ mol_attend_W.T + b ----------------
__global__ __launch_bounds__(256) void k_av(const float* __restrict__ act,
                                            const float* __restrict__ MWaT,
                                            const float* __restrict__ mab,
                                            float* __restrict__ AV) {
    int g0 = blockIdx.x * 8;
    int t = threadIdx.x;
    __shared__ float xs[8][FP];
    for (int a = 0; a < 8; ++a) xs[a][t] = act[(size_t)(g0 + a) * FP + t];
    __syncthreads();
    float acc[8];
    float bb2 = mab[t];
#pragma unroll
    for (int a = 0; a < 8; ++a) acc[a] = bb2;
    for (int i = 0; i < FP; ++i) {
        float w = MWaT[i * FP + t];
#pragma unroll
        for (int a = 0; a < 8; ++a) acc[a] += xs[a][i] * w;
    }
    for (int a = 0; a < 8; ++a) AV[(size_t)(g0 + a) * FP + t] = acc[a];
}

// ---------------- mol attention + mol GRU ----------------
__global__ __launch_bounds__(256) void k_mol_step(int step,
        const float* __restrict__ act,
        const float* __restrict__ AV,
        float* __restrict__ molF,
        const float* __restrict__ mask,
        const float* __restrict__ mAw, const float* __restrict__ mAb,
        const float* __restrict__ MihT, const float* __restrict__ MhhT,
        const float* __restrict__ mbih, const float* __restrict__ mbhh,
        float* __restrict__ o_mfv, float* __restrict__ o_unb,
        float* __restrict__ o_mawv, float* __restrict__ o_molfeat) {
    int b = blockIdx.x, t = threadIdx.x;
    int wave = t >> 6, lane = t & 63;
    __shared__ float am[FP], hh[FP], cx[FP];
    __shared__ float S2[LL], mw[LL];
    __shared__ float red[4];

    float hprev = molF[b * FP + t];
    hh[t] = hprev;
    am[t] = fmaxf(hprev, 0.f);
    __syncthreads();

    float v = am[t] * mAw[t];
#pragma unroll
    for (int off = 32; off >= 1; off >>= 1) v += __shfl_xor(v, off);
    if (lane == 0) red[wave] = v;
    __syncthreads();
    float s_self = red[0] + red[1] + red[2] + red[3];

    for (int l = wave; l < LL; l += 4) {
        float v2 = 0.f;
#pragma unroll
        for (int q = 0; q < 4; ++q) {
            int i = lane + 64 * q;
            v2 += act[((size_t)b * LL + l) * FP + i] * mAw[FP + i];
        }
#pragma unroll
        for (int off = 32; off >= 1; off >>= 1) v2 += __shfl_xor(v2, off);
        if (lane == 0) S2[l] = v2;
    }
    __syncthreads();

    if (t < LL) {
        float s = fmaxf(s_self + S2[t] + mAb[0], 0.f);
        if (mask[b * LL + t] == 0.f) s += -9e8f;
        S2[t] = s;
    }
    __syncthreads();

    float m = -1e30f;
    for (int l = 0; l < LL; ++l) m = fmaxf(m, S2[l]);
    float den = 0.f;
    for (int l = 0; l < LL; ++l) den += expf(S2[l] - m);
    if (t < LL) {
        float w = expf(S2[t] - m) / den * mask[b * LL + t];
        mw[t] = w;
        o_mawv[(size_t)step * (BB * LL) + b * LL + t] = w;
    }
    __syncthreads();

    float acc = 0.f;
    for (int l = 0; l < LL; ++l) acc += mw[l] * AV[((size_t)b * LL + l) * FP + t];
    cx[t] = fmaxf(acc, 0.f);
    __syncthreads();

    float air = mbih[t], aiz = mbih[FP + t], ain = mbih[2 * FP + t];
    float ahr = mbhh[t], ahz = mbhh[FP + t], ahn = mbhh[2 * FP + t];
    for (int i = 0; i < FP; ++i) {
        float c = cx[i], h = hh[i];
        air += c * MihT[i * 768 + t];
        aiz += c * MihT[i * 768 + FP + t];
        ain += c * MihT[i * 768 + 2 * FP + t];
        ahr += h * MhhT[i * 768 + t];
        ahz += h * MhhT[i * 768 + FP + t];
        ahn += h * MhhT[i * 768 + 2 * FP + t];
    }
    float r = 1.f / (1.f + expf(-(air + ahr)));
    float z = 1.f / (1.f + expf(-(aiz + ahz)));
    float n = tanhf(ain + r * ahn);
    float hn = (1.f - z) * n + z * hprev;

    molF[b * FP + t] = hn;
    o_unb[(size_t)(step + 1) * (BB * FP) + b * FP + t] = hn;
    o_mfv[(size_t)(step + 1) * (BB * FP) + b * FP + t] = fmaxf(hn, 0.f);
    if (step == TT - 1) o_molfeat[b * FP + t] = hn;
}

extern "C" void kernel_launch(void* const* d_in, const int* in_sizes, int n_in,
                              void* d_out, int out_size, void* d_ws, size_t ws_size,
                              hipStream_t stream) {
    const float* atom_list = (const float*)d_in[0];
    const float* bond_list = (const float*)d_in[1];
    const int*   adeg      = (const int*)d_in[2];
    const int*   bdeg      = (const int*)d_in[3];
    const float* amask     = (const float*)d_in[4];
    const float* atom_fc_W = (const float*)d_in[5];
    const float* atom_fc_b = (const float*)d_in[6];
    const float* nfc_W     = (const float*)d_in[7];
    const float* nfc_b     = (const float*)d_in[8];
    const float* gwih      = (const float*)d_in[9];
    const float* gwhh      = (const float*)d_in[10];
    const float* gbih      = (const float*)d_in[11];
    const float* gbhh      = (const float*)d_in[12];
    const float* alW       = (const float*)d_in[13];
    const float* alb       = (const float*)d_in[14];
    const float* atW       = (const float*)d_in[15];
    const float* atb       = (const float*)d_in[16];
    const float* mgwih     = (const float*)d_in[17];
    const float* mgwhh     = (const float*)d_in[18];
    const float* mgbih     = (const float*)d_in[19];
    const float* mgbhh     = (const float*)d_in[20];
    const float* malW      = (const float*)d_in[21];
    const float* malb      = (const float*)d_in[22];
    const float* matW      = (const float*)d_in[23];
    const float* matb      = (const float*)d_in[24];

    const size_t BLF = (size_t)BB * LL * FP;
    float* out = (float*)d_out;
    float* O0 = out;                                 // atom_feature / h (fp32)
    float* O1 = out + BLF;                           // afv (4,B,L,FP)
    float* O2 = O1 + 4 * BLF;                        // awv (3,B,L,K)
    float* O3 = O2 + (size_t)RR * BB * LL * KK;      // mfv
    float* O4 = O3 + (size_t)(TT + 1) * BB * FP;     // mol_unb
    float* O5 = O4 + (size_t)(TT + 1) * BB * FP;     // mawv
    float* O6 = O5 + (size_t)TT * BB * LL;           // mol_feature

    // ws layout
    float* ws = (float*)d_ws;
    short* XB   = (short*)ws;                        // BLF shorts: wn bf16
    short* XB2  = XB + BLF;                          // BLF shorts: ctx bf16
    short* HBb  = XB + 2 * BLF;                      // BLF shorts: h bf16
    short* ACTB = XB + 3 * BLF;                      // BLF shorts: relu(h) bf16
    float* AV   = ws;                                // BLF floats, aliases XB+XB2 (mol phase)
    float* rest = ws + 2 * BLF;
    short* ApreB = (short*)rest;                     // BLF shorts
    float* SW    = rest + BLF / 2;                   // B*L floats
    float* MOLF  = SW + (size_t)BB * LL;
    float* WafcT = MOLF + (size_t)BB * FP;
    float* WnT   = WafcT + AA * FP;
    float* MWaT  = WnT + (AA + BDD) * FP;
    float* MihT  = MWaT + (size_t)FP * FP;
    float* MhhT  = MihT + (size_t)FP * 768;
    short* GW    = (short*)(MhhT + (size_t)FP * 768);   // RR*2*(8*48*512) shorts
    short* WaF   = GW + (size_t)RR * 2 * 8 * 48 * 512;  // RR*(8*16*512) shorts
    (void)ws_size; (void)in_sizes; (void)n_in; (void)out_size;

    auto tr = [&](const float* src, float* dst, int O, int I) {
        int n = O * I;
        k_transpose<<<(n + 255) / 256, 256, 0, stream>>>(src, dst, O, I);
    };
    tr(atom_fc_W, WafcT, FP, AA);
    tr(nfc_W, WnT, FP, AA + BDD);
    tr(matW, MWaT, FP, FP);
    tr(mgwih, MihT, 768, FP);
    tr(mgwhh, MhhT, 768, FP);

    {
        int n = RR * 2 * 8 * 48 * 512;
        k_prep_gruw<<<(n + 255) / 256, 256, 0, stream>>>(gwih, gwhh, GW);
        int n2 = RR * 8 * 16 * 512;
        k_prep_waf<<<(n2 + 255) / 256, 256, 0, stream>>>(atW, WaF);
    }

    k_atom_fc8<<<BB * LL / 8, 256, 0, stream>>>(atom_list, WafcT, atom_fc_b, O1, O0, HBb);
    k_apre<<<BB * LL / 8, 256, 0, stream>>>(atom_list, WnT, nfc_b, ApreB);

    const size_t wblk = (size_t)8 * 48 * 512;
    const size_t ablk = (size_t)8 * 16 * 512;
    for (int d = 0; d < RR; ++d) {
        const short* selfB = (d == 0) ? HBb : ACTB;
        if (d == 0) {
            k_awn2<1><<<BB * 2, 512, 0, stream>>>(selfB, ApreB, bond_list, adeg, bdeg,
                    WnT, alW, alb, XB, SW, O2);
        } else {
            k_awn2<0><<<BB * 2, 512, 0, stream>>>(selfB, ACTB, bond_list, adeg, bdeg,
                    WnT, alW + (size_t)d * 2 * FP, alb + d,
                    XB, SW, O2 + (size_t)d * BB * LL * KK);
        }
        k_ctx_mfma<<<BB * LL / 32, 512, 0, stream>>>(XB, SW, WaF + (size_t)d * ablk,
                atb + (size_t)d * FP, XB2);
        if (d == RR - 1) {
            k_gru_mfma<1><<<BB * LL / 32, 512, 0, stream>>>(XB2, HBb, O0,
                    GW + (size_t)(d * 2 + 0) * wblk, GW + (size_t)(d * 2 + 1) * wblk,
                    gbih + (size_t)d * 768, gbhh + (size_t)d * 768,
                    O1 + (size_t)(d + 1) * BLF, HBb, ACTB);
        } else {
            k_gru_mfma<0><<<BB * LL / 32, 512, 0, stream>>>(XB2, HBb, O0,
                    GW + (size_t)(d * 2 + 0) * wblk, GW + (size_t)(d * 2 + 1) * wblk,
                    gbih + (size_t)d * 768, gbhh + (size_t)d * 768,
                    O1 + (size_t)(d + 1) * BLF, HBb, ACTB);
        }
    }

    const float* actFin = O1 + (size_t)RR * BLF;
    k_mol_reduce<<<BB, 256, 0, stream>>>(O0, actFin, amask, O4, O3, MOLF);
    k_av<<<BB * LL / 8, 256, 0, stream>>>(actFin, MWaT, matb, AV);
    for (int st = 0; st < TT; ++st) {
        k_mol_step<<<BB, 256, 0, stream>>>(st, actFin, AV, MOLF, amask,
                malW, malb, MihT, MhhT, mgbih, mgbhh,
                O3, O4, O5, O6);
    }
}

// Round 9
// 656.363 us; speedup vs baseline: 1.5934x; 1.0108x over previous
//
#include <hip/hip_runtime.h>
#include <hip/hip_bf16.h>

// Dims
#define BB 256
#define LL 128
#define AA 39
#define BDD 10
#define KK 6
#define MM 256
#define FP 256
#define RR 3
#define TT 2

using short8  = __attribute__((ext_vector_type(8))) short;
using short4v = __attribute__((ext_vector_type(4))) short;
using f32x4   = __attribute__((ext_vector_type(4))) float;
using f32x2   = __attribute__((ext_vector_type(2))) float;

__device__ __forceinline__ short f2bf(float f) {
    union { float f; unsigned u; } v; v.f = f;
    unsigned u = v.u;
    u += 0x7fffu + ((u >> 16) & 1u);   // round-to-nearest-even
    return (short)(u >> 16);
}
__device__ __forceinline__ float bf2f(short s) {
    union { unsigned u; float f; } v; v.u = ((unsigned)(unsigned short)s) << 16;
    return v.f;
}
__device__ __forceinline__ float wred64(float v) {
#pragma unroll
    for (int off = 32; off >= 1; off >>= 1) v += __shfl_xor(v, off);
    return v;
}

// ---------------- transpose: dst[i*O+o] = src[o*I+i] ----------------
__global__ __launch_bounds__(256) void k_transpose(const float* __restrict__ src,
                                                   float* __restrict__ dst, int O, int I) {
    int idx = blockIdx.x * 256 + threadIdx.x;
    if (idx >= O * I) return;
    int o = idx / I, i = idx - o * I;
    dst[i * O + o] = src[idx];
}

// ---------------- pack ALL GRU weights into MFMA fragment-major bf16 ----------------
// out layout: [d][mat][ks(8)][nt(48)][lane(64)][j(8)]
__global__ __launch_bounds__(256) void k_prep_gruw(const float* __restrict__ gwih,
                                                   const float* __restrict__ gwhh,
                                                   short* __restrict__ out) {
    int idx = blockIdx.x * 256 + threadIdx.x;
    if (idx >= RR * 2 * 8 * 48 * 512) return;
    int j = idx & 7;
    int lane = (idx >> 3) & 63;
    int blk = idx >> 9;
    int nt = blk % 48;
    int ks = (blk / 48) % 8;
    int mat = (blk / (48 * 8)) % 2;
    int d = blk / (48 * 8 * 2);
    int n = nt * 16 + (lane & 15);
    int k = ks * 32 + (lane >> 4) * 8 + j;
    const float* W = mat ? gwhh : gwih;
    out[idx] = f2bf(W[((size_t)d * 768 + n) * FP + k]);
}

// ---------------- pack ALL attend weights: [d][ks(8)][nt(16)][lane][j] ----------------
__global__ __launch_bounds__(256) void k_prep_waf(const float* __restrict__ atW,
                                                  short* __restrict__ out) {
    int idx = blockIdx.x * 256 + threadIdx.x;
    if (idx >= RR * 8 * 16 * 512) return;
    int j = idx & 7;
    int lane = (idx >> 3) & 63;
    int blk = idx >> 9;
    int nt = blk % 16;
    int ks = (blk / 16) % 8;
    int d = blk / 128;
    int n = nt * 16 + (lane & 15);
    int k = ks * 32 + (lane >> 4) * 8 + j;
    out[idx] = f2bf(atW[(size_t)d * FP * FP + (size_t)n * FP + k]);
}

// ---------------- pack mol GRU weights transposed bf16: dst[i*768+n]=W[n*FP+i] ----
__global__ __launch_bounds__(256) void k_prep_molw(const float* __restrict__ mih,
                                                   const float* __restrict__ mhh,
                                                   short* __restrict__ outih,
                                                   short* __restrict__ outhh) {
    int idx = blockIdx.x * 256 + threadIdx.x;
    if (idx >= FP * 768) return;
    int i = idx / 768, n = idx % 768;
    outih[idx] = f2bf(mih[(size_t)n * FP + i]);
    outhh[idx] = f2bf(mhh[(size_t)n * FP + i]);
}

// ---------------- atom fc (8 atoms/block) ----------------
__global__ __launch_bounds__(256) void k_atom_fc8(const float* __restrict__ atom_list,
                                                  const float* __restrict__ WafcT,
                                                  const float* __restrict__ bias,
                                                  float* __restrict__ out_pre,
                                                  float* __restrict__ hbuf,
                                                  short* __restrict__ hb16) {
    int g0 = blockIdx.x * 8;
    int t = threadIdx.x;
    __shared__ float x[8][AA];
    for (int i = t; i < 8 * AA; i += 256) x[i / AA][i % AA] = atom_list[(size_t)g0 * AA + i];
    __syncthreads();
    float acc[8];
    float bv = bias[t];
#pragma unroll
    for (int a = 0; a < 8; ++a) acc[a] = bv;
    for (int i = 0; i < AA; ++i) {
        float w = WafcT[i * FP + t];
#pragma unroll
        for (int a = 0; a < 8; ++a) acc[a] += x[a][i] * w;
    }
#pragma unroll
    for (int a = 0; a < 8; ++a) {
        size_t idx = (size_t)(g0 + a) * FP + t;
        out_pre[idx] = acc[a];
        float rl = fmaxf(acc[a], 0.f);
        hbuf[idx] = rl;
        hb16[idx] = f2bf(rl);   // h0 = relu(pre); also ACT source for d=0
    }
}

// ---------------- ApreB = bf16(atom_list @ WnA^T + bn) ----------------
__global__ __launch_bounds__(256) void k_apre(const float* __restrict__ atom_list,
                                              const float* __restrict__ WnT,
                                              const float* __restrict__ bn,
                                              short* __restrict__ ApreB) {
    int g0 = blockIdx.x * 8;
    int t = threadIdx.x;
    __shared__ float x[8][AA];
    for (int i = t; i < 8 * AA; i += 256) x[i / AA][i % AA] = atom_list[(size_t)g0 * AA + i];
    __syncthreads();
    float acc[8];
    float bv = bn[t];
#pragma unroll
    for (int a = 0; a < 8; ++a) acc[a] = bv;
    for (int i = 0; i < AA; ++i) {
        float w = WnT[i * FP + t];
#pragma unroll
        for (int a = 0; a < 8; ++a) acc[a] += x[a][i] * w;
    }
#pragma unroll
    for (int a = 0; a < 8; ++a) ApreB[(size_t)(g0 + a) * FP + t] = f2bf(acc[a]);
}

// ---------------- attention: per-molecule LDS-staged gather ----------------
template<int IS_D0>
__global__ __launch_bounds__(512) void k_awn2(
        const short* __restrict__ ACTB,     // relu'd act bf16 (self dots)
        const short* __restrict__ SRC,      // neighbor source to stage
        const float* __restrict__ bond_list,
        const int* __restrict__ adeg, const int* __restrict__ bdeg,
        const float* __restrict__ WnT,      // bond rows AA..AA+BDD-1 (d0 only)
        const float* __restrict__ alignW, const float* __restrict__ alignBp,
        short* __restrict__ wn_out, float* __restrict__ sw_out,
        float* __restrict__ awv_out) {
    __shared__ short snb[LL * FP];          // 64 KB
    const int b = blockIdx.x >> 1;
    const int half = blockIdx.x & 1;
    const int t = threadIdx.x;
    const int wave = t >> 6, lane = t & 63;

    {
        const char* src = (const char*)(SRC + (size_t)b * LL * FP);
#pragma unroll
        for (int it = 0; it < 8; ++it) {
            int off = it * 8192 + wave * 1024 + lane * 16;
            __builtin_amdgcn_global_load_lds(
                (const __attribute__((address_space(1))) void*)(src + off),
                (__attribute__((address_space(3))) void*)((char*)snb + it * 8192 + wave * 1024),
                16, 0, 0);
        }
    }

    f32x4 w0 = *(const f32x4*)(alignW + lane * 4);
    f32x4 w1 = *(const f32x4*)(alignW + FP + lane * 4);
    float bias = alignBp[0];

    float wnt[IS_D0 ? BDD : 1][4];
    if constexpr (IS_D0) {
#pragma unroll
        for (int i = 0; i < BDD; ++i) {
            f32x4 v = *(const f32x4*)(WnT + (AA + i) * FP + lane * 4);
#pragma unroll
            for (int q = 0; q < 4; ++q) wnt[i][q] = v[q];
        }
    }

    __syncthreads();   // staging complete

#pragma unroll
    for (int ai = 0; ai < 8; ++ai) {
        const int al = half * 64 + wave * 8 + ai;
        const int ga = b * LL + al;

        short4v sv = *(const short4v*)(ACTB + (size_t)ga * FP + lane * 4);
        float ss = wred64(bf2f(sv[0]) * w0[0] + bf2f(sv[1]) * w0[1] +
                          bf2f(sv[2]) * w0[2] + bf2f(sv[3]) * w0[3]);

        int jx[KK];
#pragma unroll
        for (int k = 0; k < KK; ++k) jx[k] = adeg[ga * KK + k];

        float nf[KK][4];
        float sc[KK];
#pragma unroll
        for (int k = 0; k < KK; ++k) {
            short4v nv = *(const short4v*)(snb + jx[k] * FP + lane * 4);
            float f0 = bf2f(nv[0]), f1 = bf2f(nv[1]), f2 = bf2f(nv[2]), f3 = bf2f(nv[3]);
            if constexpr (IS_D0) {
                int bi = bdeg[ga * KK + k];
                const float* bp = bond_list + ((size_t)b * MM + bi) * BDD;
                float bb[BDD];
#pragma unroll
                for (int i = 0; i < 5; ++i) {
                    f32x2 v2 = *(const f32x2*)(bp + 2 * i);
                    bb[2 * i] = v2[0]; bb[2 * i + 1] = v2[1];
                }
                float b0 = 0.f, b1 = 0.f, b2 = 0.f, b3 = 0.f;
#pragma unroll
                for (int i = 0; i < BDD; ++i) {
                    b0 += bb[i] * wnt[i][0]; b1 += bb[i] * wnt[i][1];
                    b2 += bb[i] * wnt[i][2]; b3 += bb[i] * wnt[i][3];
                }
                f0 = fmaxf(f0 + b0, 0.f); f1 = fmaxf(f1 + b1, 0.f);
                f2 = fmaxf(f2 + b2, 0.f); f3 = fmaxf(f3 + b3, 0.f);
            }
            nf[k][0] = f0; nf[k][1] = f1; nf[k][2] = f2; nf[k][3] = f3;
            float s2 = wred64(f0 * w1[0] + f1 * w1[1] + f2 * w1[2] + f3 * w1[3]);
            float s = fmaxf(ss + s2 + bias, 0.f);
            if (jx[k] == LL - 1) s -= 9.0f;
            sc[k] = s;
        }

        float m = sc[0];
#pragma unroll
        for (int k = 1; k < KK; ++k) m = fmaxf(m, sc[k]);
        float e[KK], den = 0.f;
#pragma unroll
        for (int k = 0; k < KK; ++k) { e[k] = expf(sc[k] - m); den += e[k]; }
        float aw[KK], sumaw = 0.f;
#pragma unroll
        for (int k = 0; k < KK; ++k) {
            aw[k] = (jx[k] == LL - 1) ? 0.f : e[k] / den;
            sumaw += aw[k];
        }
        if (lane < KK) {
            float av = aw[0];
#pragma unroll
            for (int k = 1; k < KK; ++k) if (lane == k) av = aw[k];
            awv_out[(size_t)ga * KK + lane] = av;
        }
        if (lane == 0) sw_out[ga] = sumaw;

        short4v wo;
#pragma unroll
        for (int q = 0; q < 4; ++q) {
            float w = 0.f;
#pragma unroll
            for (int k = 0; k < KK; ++k) w += aw[k] * nf[k][q];
            wo[q] = f2bf(w);
        }
        *(short4v*)(wn_out + (size_t)ga * FP + lane * 4) = wo;
    }
}

// ---------------- ctx = relu(WN @ Wa^T + sumaw*ab), LDS-staged B, ks-stagger ----
__global__ __launch_bounds__(512) void k_ctx_mfma(
        const short* __restrict__ XB,      // wn bf16
        const float* __restrict__ SW,
        const short* __restrict__ WaF,     // frag-major (8,16,64,8)
        const float* __restrict__ ab,
        short* __restrict__ ctx_out) {
    __shared__ short lds[2][8192];         // 2 x 16KB
    const int t = threadIdx.x;
    const int wave = t >> 6, lane = t & 63;
    const int abase = blockIdx.x * 32 + (wave >> 2) * 16;
    const int wn4 = wave & 3;
    const int lr = lane & 15, lk = lane >> 4;
    const int kofs = blockIdx.x & 7;

#define CSTAGE(i) do { \
        int ke_ = ((i) + kofs) & 7; \
        _Pragma("unroll") \
        for (int e = 0; e < 2; ++e) { \
            int f = wave * 2 + e; \
            __builtin_amdgcn_global_load_lds( \
                (const __attribute__((address_space(1))) void*)(WaF + (size_t)(ke_ * 16 + f) * 512 + lane * 8), \
                (__attribute__((address_space(3))) void*)(&lds[(i) & 1][f * 512]), 16, 0, 0); \
        } } while (0)

    f32x4 acc[4] = {};
    const short8* xrow = (const short8*)(XB + (size_t)(abase + lr) * FP);

    CSTAGE(0);
#pragma unroll
    for (int i = 0; i < 8; ++i) {
        int ke = (i + kofs) & 7;
        short8 ax = xrow[ke * 4 + lk];
        __syncthreads();
        if (i < 7) CSTAGE(i + 1);
#pragma unroll
        for (int sub = 0; sub < 4; ++sub) {
            int nt = wn4 * 4 + sub;
            short8 bf = *(const short8*)(&lds[i & 1][nt * 512 + lane * 8]);
            acc[sub] = __builtin_amdgcn_mfma_f32_16x16x32_bf16(ax, bf, acc[sub], 0, 0, 0);
        }
    }
#undef CSTAGE

#pragma unroll
    for (int sub = 0; sub < 4; ++sub) {
        int c = wn4 * 64 + sub * 16 + lr;
        float abc = ab[c];
#pragma unroll
        for (int q = 0; q < 4; ++q) {
            int atom = abase + lk * 4 + q;
            float v = acc[sub][q] + SW[atom] * abc;
            ctx_out[(size_t)atom * FP + c] = f2bf(fmaxf(v, 0.f));
        }
    }
}

// ---------------- fused MFMA GRU v4: 64 atoms/block, 2 row-groups/wave ----------
// 512 blocks x 512 thr. Weight traffic per dispatch halves vs 32-atom blocks
// (393 MB L2); 12 MFMA/wave/phase doubles compute per staged byte.
// 32 f32x4 accumulators (128 VGPR) + working regs ~ 170 -> no launch_bounds cap
// (round-7 lesson: capping forced accumulator spill).
template<int LAST>
__global__ __launch_bounds__(512) void k_gru_mfma(
        const short* __restrict__ XB,     // ctx bf16
        const short* __restrict__ HBl,    // h bf16 (read)
        float* __restrict__ hbuf,         // h fp32 (read old, write new)
        const short* __restrict__ Bih,    // frag-major (8,48,64,8)
        const short* __restrict__ Bhh,
        const float* __restrict__ bih, const float* __restrict__ bhh,
        float* __restrict__ act_out,
        short* __restrict__ HB_out,
        short* __restrict__ ACT_out) {
    __shared__ short lds[2][12288];       // 2 x 24KB
    const int t = threadIdx.x;
    const int wave = t >> 6, lane = t & 63;
    const int rh = wave >> 2;             // row half (32 atoms each)
    const int wn = wave & 3;              // col slice
    const int lr = lane & 15, lk = lane >> 4;
    const int bid = blockIdx.x;
    const int kofs = bid & 7;
    const int abase = bid * 64 + rh * 32;

#define PKS(p)  ((((p) >> 2) + kofs) & 7)
#define STAGEP(p) do { \
        const short* base_ = ((((p) >> 1) & 1) ? Bhh : Bih) + (size_t)PKS(p) * 24576; \
        const int h_ = (p) & 1; \
        _Pragma("unroll") \
        for (int e = 0; e < 3; ++e) { \
            int j = wave * 3 + e; \
            int nt = 4 * (j >> 1) + 2 * h_ + (j & 1); \
            __builtin_amdgcn_global_load_lds( \
                (const __attribute__((address_space(1))) void*)(base_ + nt * 512 + lane * 8), \
                (__attribute__((address_space(3))) void*)(&lds[(p) & 1][j * 512]), 16, 0, 0); \
        } } while (0)

    const short8* xrow0 = (const short8*)(XB + (size_t)(abase + lr) * FP);
    const short8* hrow0 = (const short8*)(HBl + (size_t)(abase + lr) * FP);
    const short8* xrow1 = (const short8*)(XB + (size_t)(abase + 16 + lr) * FP);
    const short8* hrow1 = (const short8*)(HBl + (size_t)(abase + 16 + lr) * FP);

    f32x4 acc_rz[2][8] = {};   // [rg][g(2)*4+sub]: gi+gh fused
    f32x4 acc_in[2][4] = {};
    f32x4 acc_hn[2][4] = {};

    STAGEP(0);
    short8 ax0{}, ah0{}, ax1{}, ah1{};
#pragma unroll
    for (int p = 0; p < 32; ++p) {
        const int h_ = p & 1;
        const int mat = (p >> 1) & 1;
        if ((p & 3) == 0) {
            int ke = PKS(p);
            ax0 = xrow0[ke * 4 + lk];
            ah0 = hrow0[ke * 4 + lk];
            ax1 = xrow1[ke * 4 + lk];
            ah1 = hrow1[ke * 4 + lk];
        }
        __syncthreads();          // lds[p&1] staged; prev reads of lds[(p+1)&1] done
        if (p < 31) STAGEP(p + 1);
#pragma unroll
        for (int rg = 0; rg < 2; ++rg) {
            const short8 a8 = mat ? (rg ? ah1 : ah0) : (rg ? ax1 : ax0);
#pragma unroll
            for (int g = 0; g < 3; ++g) {
#pragma unroll
                for (int s2 = 0; s2 < 2; ++s2) {
                    const int sub = 2 * h_ + s2;
                    const int j = ((4 * g + wn) << 1) | s2;
                    short8 bf = *(const short8*)(&lds[p & 1][j * 512 + lane * 8]);
                    if (g < 2)
                        acc_rz[rg][g * 4 + sub] = __builtin_amdgcn_mfma_f32_16x16x32_bf16(a8, bf, acc_rz[rg][g * 4 + sub], 0, 0, 0);
                    else if (mat)
                        acc_hn[rg][sub] = __builtin_amdgcn_mfma_f32_16x16x32_bf16(a8, bf, acc_hn[rg][sub], 0, 0, 0);
                    else
                        acc_in[rg][sub] = __builtin_amdgcn_mfma_f32_16x16x32_bf16(a8, bf, acc_in[rg][sub], 0, 0, 0);
                }
            }
        }
    }
    __syncthreads();   // all HBl reads done before HB_out writes
#undef STAGEP
#undef PKS

#pragma unroll
    for (int sub = 0; sub < 4; ++sub) {
        int c = wn * 64 + sub * 16 + lr;
        float brz_r = bih[c] + bhh[c];
        float brz_z = bih[FP + c] + bhh[FP + c];
        float bin_ = bih[2 * FP + c];
        float bhn = bhh[2 * FP + c];
#pragma unroll
        for (int rg = 0; rg < 2; ++rg) {
#pragma unroll
            for (int q = 0; q < 4; ++q) {
                int atom = abase + rg * 16 + lk * 4 + q;
                size_t idx = (size_t)atom * FP + c;
                float hold = hbuf[idx];
                float r = 1.f / (1.f + expf(-(acc_rz[rg][0 * 4 + sub][q] + brz_r)));
                float z = 1.f / (1.f + expf(-(acc_rz[rg][1 * 4 + sub][q] + brz_z)));
                float n = tanhf(acc_in[rg][sub][q] + bin_ + r * (acc_hn[rg][sub][q] + bhn));
                float hn = (1.f - z) * n + z * hold;
                float rl = fmaxf(hn, 0.f);
                hbuf[idx] = hn;
                act_out[idx] = rl;
                if constexpr (!LAST) {
                    HB_out[idx] = f2bf(hn);
                    ACT_out[idx] = f2bf(rl);
                }
            }
        }
    }
}

// ---------------- mol reductions ----------------
__global__ __launch_bounds__(256) void k_mol_reduce(const float* __restrict__ hbuf,
                                                    const float* __restrict__ act,
                                                    const float* __restrict__ mask,
                                                    float* __restrict__ o_unb0,
                                                    float* __restrict__ o_mfv0,
                                                    float* __restrict__ molF) {
    int b = blockIdx.x, t = threadIdx.x;
    float s1 = 0.f, s2 = 0.f;
    for (int l = 0; l < LL; ++l) {
        float mk = mask[b * LL + l];
        s1 += hbuf[((size_t)b * LL + l) * FP + t] * mk;
        s2 += act[((size_t)b * LL + l) * FP + t] * mk;
    }
    o_unb0[b * FP + t] = s1;
    o_mfv0[b * FP + t] = s2;
    molF[b * FP + t] = s2;
}

// ---------------- AV = act @ mol_attend_W.T + b ----------------
__global__ __launch_bounds__(256) void k_av(const float* __restrict__ act,
                                            const float* __restrict__ MWaT,
                                            const float* __restrict__ mab,
                                            float* __restrict__ AV) {
    int g0 = blockIdx.x * 8;
    int t = threadIdx.x;
    __shared__ float xs[8][FP];
    for (int a = 0; a < 8; ++a) xs[a][t] = act[(size_t)(g0 + a) * FP + t];
    __syncthreads();
    float acc[8];
    float bb2 = mab[t];
#pragma unroll
    for (int a = 0; a < 8; ++a) acc[a] = bb2;
    for (int i = 0; i < FP; ++i) {
        float w = MWaT[i * FP + t];
#pragma unroll
        for (int a = 0; a < 8; ++a) acc[a] += xs[a][i] * w;
    }
    for (int a = 0; a < 8; ++a) AV[(size_t)(g0 + a) * FP + t] = acc[a];
}

// ---------------- mol attention + mol GRU (bf16 weights) ----------------
__global__ __launch_bounds__(256) void k_mol_step(int step,
        const float* __restrict__ act,
        const float* __restrict__ AV,
        float* __restrict__ molF,
        const float* __restrict__ mask,
        const float* __restrict__ mAw, const float* __restrict__ mAb,
        const short* __restrict__ MihB, const short* __restrict__ MhhB,
        const float* __restrict__ mbih, const float* __restrict__ mbhh,
        float* __restrict__ o_mfv, float* __restrict__ o_unb,
        float* __restrict__ o_mawv, float* __restrict__ o_molfeat) {
    int b = blockIdx.x, t = threadIdx.x;
    int wave = t >> 6, lane = t & 63;
    __shared__ float am[FP], hh[FP], cx[FP];
    __shared__ float S2[LL], mw[LL];
    __shared__ float red[4];

    float hprev = molF[b * FP + t];
    hh[t] = hprev;
    am[t] = fmaxf(hprev, 0.f);
    __syncthreads();

    float v = am[t] * mAw[t];
#pragma unroll
    for (int off = 32; off >= 1; off >>= 1) v += __shfl_xor(v, off);
    if (lane == 0) red[wave] = v;
    __syncthreads();
    float s_self = red[0] + red[1] + red[2] + red[3];

    for (int l = wave; l < LL; l += 4) {
        float v2 = 0.f;
#pragma unroll
        for (int q = 0; q < 4; ++q) {
            int i = lane + 64 * q;
            v2 += act[((size_t)b * LL + l) * FP + i] * mAw[FP + i];
        }
#pragma unroll
        for (int off = 32; off >= 1; off >>= 1) v2 += __shfl_xor(v2, off);
        if (lane == 0) S2[l] = v2;
    }
    __syncthreads();

    if (t < LL) {
        float s = fmaxf(s_self + S2[t] + mAb[0], 0.f);
        if (mask[b * LL + t] == 0.f) s += -9e8f;
        S2[t] = s;
    }
    __syncthreads();

    float m = -1e30f;
    for (int l = 0; l < LL; ++l) m = fmaxf(m, S2[l]);
    float den = 0.f;
    for (int l = 0; l < LL; ++l) den += expf(S2[l] - m);
    if (t < LL) {
        float w = expf(S2[t] - m) / den * mask[b * LL + t];
        mw[t] = w;
        o_mawv[(size_t)step * (BB * LL) + b * LL + t] = w;
    }
    __syncthreads();

    float acc = 0.f;
    for (int l = 0; l < LL; ++l) acc += mw[l] * AV[((size_t)b * LL + l) * FP + t];
    cx[t] = fmaxf(acc, 0.f);
    __syncthreads();

    float air = mbih[t], aiz = mbih[FP + t], ain = mbih[2 * FP + t];
    float ahr = mbhh[t], ahz = mbhh[FP + t], ahn = mbhh[2 * FP + t];
    for (int i = 0; i < FP; ++i) {
        float c = cx[i], h = hh[i];
        air += c * bf2f(MihB[i * 768 + t]);
        aiz += c * bf2f(MihB[i * 768 + FP + t]);
        ain += c * bf2f(MihB[i * 768 + 2 * FP + t]);
        ahr += h * bf2f(MhhB[i * 768 + t]);
        ahz += h * bf2f(MhhB[i * 768 + FP + t]);
        ahn += h * bf2f(MhhB[i * 768 + 2 * FP + t]);
    }
    float r = 1.f / (1.f + expf(-(air + ahr)));
    float z = 1.f / (1.f + expf(-(aiz + ahz)));
    float n = tanhf(ain + r * ahn);
    float hn = (1.f - z) * n + z * hprev;

    molF[b * FP + t] = hn;
    o_unb[(size_t)(step + 1) * (BB * FP) + b * FP + t] = hn;
    o_mfv[(size_t)(step + 1) * (BB * FP) + b * FP + t] = fmaxf(hn, 0.f);
    if (step == TT - 1) o_molfeat[b * FP + t] = hn;
}

extern "C" void kernel_launch(void* const* d_in, const int* in_sizes, int n_in,
                              void* d_out, int out_size, void* d_ws, size_t ws_size,
                              hipStream_t stream) {
    const float* atom_list = (const float*)d_in[0];
    const float* bond_list = (const float*)d_in[1];
    const int*   adeg      = (const int*)d_in[2];
    const int*   bdeg      = (const int*)d_in[3];
    const float* amask     = (const float*)d_in[4];
    const float* atom_fc_W = (const float*)d_in[5];
    const float* atom_fc_b = (const float*)d_in[6];
    const float* nfc_W     = (const float*)d_in[7];
    const float* nfc_b     = (const float*)d_in[8];
    const float* gwih      = (const float*)d_in[9];
    const float* gwhh      = (const float*)d_in[10];
    const float* gbih      = (const float*)d_in[11];
    const float* gbhh      = (const float*)d_in[12];
    const float* alW       = (const float*)d_in[13];
    const float* alb       = (const float*)d_in[14];
    const float* atW       = (const float*)d_in[15];
    const float* atb       = (const float*)d_in[16];
    const float* mgwih     = (const float*)d_in[17];
    const float* mgwhh     = (const float*)d_in[18];
    const float* mgbih     = (const float*)d_in[19];
    const float* mgbhh     = (const float*)d_in[20];
    const float* malW      = (const float*)d_in[21];
    const float* malb      = (const float*)d_in[22];
    const float* matW      = (const float*)d_in[23];
    const float* matb      = (const float*)d_in[24];

    const size_t BLF = (size_t)BB * LL * FP;
    float* out = (float*)d_out;
    float* O0 = out;                                 // atom_feature / h (fp32)
    float* O1 = out + BLF;                           // afv (4,B,L,FP)
    float* O2 = O1 + 4 * BLF;                        // awv (3,B,L,K)
    float* O3 = O2 + (size_t)RR * BB * LL * KK;      // mfv
    float* O4 = O3 + (size_t)(TT + 1) * BB * FP;     // mol_unb
    float* O5 = O4 + (size_t)(TT + 1) * BB * FP;     // mawv
    float* O6 = O5 + (size_t)TT * BB * LL;           // mol_feature

    // ws layout
    float* ws = (float*)d_ws;
    short* XB   = (short*)ws;                        // BLF shorts: wn bf16
    short* XB2  = XB + BLF;                          // BLF shorts: ctx bf16
    short* HBb  = XB + 2 * BLF;                      // BLF shorts: h bf16
    short* ACTB = XB + 3 * BLF;                      // BLF shorts: relu(h) bf16
    float* AV   = ws;                                // BLF floats, aliases XB+XB2 (mol phase)
    float* rest = ws + 2 * BLF;
    short* ApreB = (short*)rest;                     // BLF shorts
    float* SW    = rest + BLF / 2;                   // B*L floats
    float* MOLF  = SW + (size_t)BB * LL;
    float* WafcT = MOLF + (size_t)BB * FP;
    float* WnT   = WafcT + AA * FP;
    float* MWaT  = WnT + (AA + BDD) * FP;
    short* MihB  = (short*)(MWaT + (size_t)FP * FP);    // FP*768 shorts
    short* MhhB  = MihB + (size_t)FP * 768;
    short* GW    = MhhB + (size_t)FP * 768;             // RR*2*(8*48*512) shorts
    short* WaF   = GW + (size_t)RR * 2 * 8 * 48 * 512;  // RR*(8*16*512) shorts
    (void)ws_size; (void)in_sizes; (void)n_in; (void)out_size;

    auto tr = [&](const float* src, float* dst, int O, int I) {
        int n = O * I;
        k_transpose<<<(n + 255) / 256, 256, 0, stream>>>(src, dst, O, I);
    };
    tr(atom_fc_W, WafcT, FP, AA);
    tr(nfc_W, WnT, FP, AA + BDD);
    tr(matW, MWaT, FP, FP);

    {
        int n = RR * 2 * 8 * 48 * 512;
        k_prep_gruw<<<(n + 255) / 256, 256, 0, stream>>>(gwih, gwhh, GW);
        int n2 = RR * 8 * 16 * 512;
        k_prep_waf<<<(n2 + 255) / 256, 256, 0, stream>>>(atW, WaF);
        int n3 = FP * 768;
        k_prep_molw<<<(n3 + 255) / 256, 256, 0, stream>>>(mgwih, mgwhh, MihB, MhhB);
    }

    k_atom_fc8<<<BB * LL / 8, 256, 0, stream>>>(atom_list, WafcT, atom_fc_b, O1, O0, HBb);
    k_apre<<<BB * LL / 8, 256, 0, stream>>>(atom_list, WnT, nfc_b, ApreB);

    const size_t wblk = (size_t)8 * 48 * 512;
    const size_t ablk = (size_t)8 * 16 * 512;
    for (int d = 0; d < RR; ++d) {
        const short* selfB = (d == 0) ? HBb : ACTB;
        if (d == 0) {
            k_awn2<1><<<BB * 2, 512, 0, stream>>>(selfB, ApreB, bond_list, adeg, bdeg,
                    WnT, alW, alb, XB, SW, O2);
        } else {
            k_awn2<0><<<BB * 2, 512, 0, stream>>>(selfB, ACTB, bond_list, adeg, bdeg,
                    WnT, alW + (size_t)d * 2 * FP, alb + d,
                    XB, SW, O2 + (size_t)d * BB * LL * KK);
        }
        k_ctx_mfma<<<BB * LL / 32, 512, 0, stream>>>(XB, SW, WaF + (size_t)d * ablk,
                atb + (size_t)d * FP, XB2);
        if (d == RR - 1) {
            k_gru_mfma<1><<<BB * LL / 64, 512, 0, stream>>>(XB2, HBb, O0,
                    GW + (size_t)(d * 2 + 0) * wblk, GW + (size_t)(d * 2 + 1) * wblk,
                    gbih + (size_t)d * 768, gbhh + (size_t)d * 768,
                    O1 + (size_t)(d + 1) * BLF, HBb, ACTB);
        } else {
            k_gru_mfma<0><<<BB * LL / 64, 512, 0, stream>>>(XB2, HBb, O0,
                    GW + (size_t)(d * 2 + 0) * wblk, GW + (size_t)(d * 2 + 1) * wblk,
                    gbih + (size_t)d * 768, gbhh + (size_t)d * 768,
                    O1 + (size_t)(d + 1) * BLF, HBb, ACTB);
        }
    }

    const float* actFin = O1 + (size_t)RR * BLF;
    k_mol_reduce<<<BB, 256, 0, stream>>>(O0, actFin, amask, O4, O3, MOLF);
    k_av<<<BB * LL / 8, 256, 0, stream>>>(actFin, MWaT, matb, AV);
    for (int st = 0; st < TT; ++st) {
        k_mol_step<<<BB, 256, 0, stream>>>(st, actFin, AV, MOLF, amask,
                malW, malb, MihB, MhhB, mgbih, mgbhh,
                O3, O4, O5, O6);
    }
}

// Round 10
// 648.778 us; speedup vs baseline: 1.6120x; 1.0117x over previous
//
#include <hip/hip_runtime.h>
#include <hip/hip_bf16.h>

// Dims
#define BB 256
#define LL 128
#define AA 39
#define BDD 10
#define KK 6
#define MM 256
#define FP 256
#define RR 3
#define TT 2

using short8  = __attribute__((ext_vector_type(8))) short;
using short4v = __attribute__((ext_vector_type(4))) short;
using f32x4   = __attribute__((ext_vector_type(4))) float;
using f32x2   = __attribute__((ext_vector_type(2))) float;

__device__ __forceinline__ short f2bf(float f) {
    union { float f; unsigned u; } v; v.f = f;
    unsigned u = v.u;
    u += 0x7fffu + ((u >> 16) & 1u);   // round-to-nearest-even
    return (short)(u >> 16);
}
__device__ __forceinline__ float bf2f(short s) {
    union { unsigned u; float f; } v; v.u = ((unsigned)(unsigned short)s) << 16;
    return v.f;
}
__device__ __forceinline__ float wred64(float v) {
#pragma unroll
    for (int off = 32; off >= 1; off >>= 1) v += __shfl_xor(v, off);
    return v;
}

// ---------------- transpose: dst[i*O+o] = src[o*I+i] ----------------
__global__ __launch_bounds__(256) void k_transpose(const float* __restrict__ src,
                                                   float* __restrict__ dst, int O, int I) {
    int idx = blockIdx.x * 256 + threadIdx.x;
    if (idx >= O * I) return;
    int o = idx / I, i = idx - o * I;
    dst[i * O + o] = src[idx];
}

// ---------------- pack ALL GRU weights into MFMA fragment-major bf16 ----------------
// out layout: [d][mat][ks(8)][nt(48)][lane(64)][j(8)]
__global__ __launch_bounds__(256) void k_prep_gruw(const float* __restrict__ gwih,
                                                   const float* __restrict__ gwhh,
                                                   short* __restrict__ out) {
    int idx = blockIdx.x * 256 + threadIdx.x;
    if (idx >= RR * 2 * 8 * 48 * 512) return;
    int j = idx & 7;
    int lane = (idx >> 3) & 63;
    int blk = idx >> 9;
    int nt = blk % 48;
    int ks = (blk / 48) % 8;
    int mat = (blk / (48 * 8)) % 2;
    int d = blk / (48 * 8 * 2);
    int n = nt * 16 + (lane & 15);
    int k = ks * 32 + (lane >> 4) * 8 + j;
    const float* W = mat ? gwhh : gwih;
    out[idx] = f2bf(W[((size_t)d * 768 + n) * FP + k]);
}

// ---------------- pack ALL attend weights: [d][ks(8)][nt(16)][lane][j] ----------------
__global__ __launch_bounds__(256) void k_prep_waf(const float* __restrict__ atW,
                                                  short* __restrict__ out) {
    int idx = blockIdx.x * 256 + threadIdx.x;
    if (idx >= RR * 8 * 16 * 512) return;
    int j = idx & 7;
    int lane = (idx >> 3) & 63;
    int blk = idx >> 9;
    int nt = blk % 16;
    int ks = (blk / 16) % 8;
    int d = blk / 128;
    int n = nt * 16 + (lane & 15);
    int k = ks * 32 + (lane >> 4) * 8 + j;
    out[idx] = f2bf(atW[(size_t)d * FP * FP + (size_t)n * FP + k]);
}

// ---------------- pack mol GRU weights transposed bf16: dst[i*768+n]=W[n*FP+i] ----
__global__ __launch_bounds__(256) void k_prep_molw(const float* __restrict__ mih,
                                                   const float* __restrict__ mhh,
                                                   short* __restrict__ outih,
                                                   short* __restrict__ outhh) {
    int idx = blockIdx.x * 256 + threadIdx.x;
    if (idx >= FP * 768) return;
    int i = idx / 768, n = idx % 768;
    outih[idx] = f2bf(mih[(size_t)n * FP + i]);
    outhh[idx] = f2bf(mhh[(size_t)n * FP + i]);
}

// ---------------- atom fc (8 atoms/block) ----------------
__global__ __launch_bounds__(256) void k_atom_fc8(const float* __restrict__ atom_list,
                                                  const float* __restrict__ WafcT,
                                                  const float* __restrict__ bias,
                                                  float* __restrict__ out_pre,
                                                  float* __restrict__ hbuf,
                                                  short* __restrict__ hb16) {
    int g0 = blockIdx.x * 8;
    int t = threadIdx.x;
    __shared__ float x[8][AA];
    for (int i = t; i < 8 * AA; i += 256) x[i / AA][i % AA] = atom_list[(size_t)g0 * AA + i];
    __syncthreads();
    float acc[8];
    float bv = bias[t];
#pragma unroll
    for (int a = 0; a < 8; ++a) acc[a] = bv;
    for (int i = 0; i < AA; ++i) {
        float w = WafcT[i * FP + t];
#pragma unroll
        for (int a = 0; a < 8; ++a) acc[a] += x[a][i] * w;
    }
#pragma unroll
    for (int a = 0; a < 8; ++a) {
        size_t idx = (size_t)(g0 + a) * FP + t;
        out_pre[idx] = acc[a];
        float rl = fmaxf(acc[a], 0.f);
        hbuf[idx] = rl;
        hb16[idx] = f2bf(rl);   // h0 = relu(pre); also ACT source for d=0
    }
}

// ---------------- ApreB = bf16(atom_list @ WnA^T + bn) ----------------
__global__ __launch_bounds__(256) void k_apre(const float* __restrict__ atom_list,
                                              const float* __restrict__ WnT,
                                              const float* __restrict__ bn,
                                              short* __restrict__ ApreB) {
    int g0 = blockIdx.x * 8;
    int t = threadIdx.x;
    __shared__ float x[8][AA];
    for (int i = t; i < 8 * AA; i += 256) x[i / AA][i % AA] = atom_list[(size_t)g0 * AA + i];
    __syncthreads();
    float acc[8];
    float bv = bn[t];
#pragma unroll
    for (int a = 0; a < 8; ++a) acc[a] = bv;
    for (int i = 0; i < AA; ++i) {
        float w = WnT[i * FP + t];
#pragma unroll
        for (int a = 0; a < 8; ++a) acc[a] += x[a][i] * w;
    }
#pragma unroll
    for (int a = 0; a < 8; ++a) ApreB[(size_t)(g0 + a) * FP + t] = f2bf(acc[a]);
}

// ---------------- attention: per-molecule LDS-staged gather ----------------
template<int IS_D0>
__global__ __launch_bounds__(512) void k_awn2(
        const short* __restrict__ ACTB,     // relu'd act bf16 (self dots)
        const short* __restrict__ SRC,      // neighbor source to stage
        const float* __restrict__ bond_list,
        const int* __restrict__ adeg, const int* __restrict__ bdeg,
        const float* __restrict__ WnT,      // bond rows AA..AA+BDD-1 (d0 only)
        const float* __restrict__ alignW, const float* __restrict__ alignBp,
        short* __restrict__ wn_out, float* __restrict__ sw_out,
        float* __restrict__ awv_out) {
    __shared__ short snb[LL * FP];          // 64 KB
    const int b = blockIdx.x >> 1;
    const int half = blockIdx.x & 1;
    const int t = threadIdx.x;
    const int wave = t >> 6, lane = t & 63;

    {
        const char* src = (const char*)(SRC + (size_t)b * LL * FP);
#pragma unroll
        for (int it = 0; it < 8; ++it) {
            int off = it * 8192 + wave * 1024 + lane * 16;
            __builtin_amdgcn_global_load_lds(
                (const __attribute__((address_space(1))) void*)(src + off),
                (__attribute__((address_space(3))) void*)((char*)snb + it * 8192 + wave * 1024),
                16, 0, 0);
        }
    }

    f32x4 w0 = *(const f32x4*)(alignW + lane * 4);
    f32x4 w1 = *(const f32x4*)(alignW + FP + lane * 4);
    float bias = alignBp[0];

    float wnt[IS_D0 ? BDD : 1][4];
    if constexpr (IS_D0) {
#pragma unroll
        for (int i = 0; i < BDD; ++i) {
            f32x4 v = *(const f32x4*)(WnT + (AA + i) * FP + lane * 4);
#pragma unroll
            for (int q = 0; q < 4; ++q) wnt[i][q] = v[q];
        }
    }

    __syncthreads();   // staging complete

#pragma unroll
    for (int ai = 0; ai < 8; ++ai) {
        const int al = half * 64 + wave * 8 + ai;
        const int ga = b * LL + al;

        short4v sv = *(const short4v*)(ACTB + (size_t)ga * FP + lane * 4);
        float ss = wred64(bf2f(sv[0]) * w0[0] + bf2f(sv[1]) * w0[1] +
                          bf2f(sv[2]) * w0[2] + bf2f(sv[3]) * w0[3]);

        int jx[KK];
#pragma unroll
        for (int k = 0; k < KK; ++k) jx[k] = adeg[ga * KK + k];

        float nf[KK][4];
        float sc[KK];
#pragma unroll
        for (int k = 0; k < KK; ++k) {
            short4v nv = *(const short4v*)(snb + jx[k] * FP + lane * 4);
            float f0 = bf2f(nv[0]), f1 = bf2f(nv[1]), f2 = bf2f(nv[2]), f3 = bf2f(nv[3]);
            if constexpr (IS_D0) {
                int bi = bdeg[ga * KK + k];
                const float* bp = bond_list + ((size_t)b * MM + bi) * BDD;
                float bb[BDD];
#pragma unroll
                for (int i = 0; i < 5; ++i) {
                    f32x2 v2 = *(const f32x2*)(bp + 2 * i);
                    bb[2 * i] = v2[0]; bb[2 * i + 1] = v2[1];
                }
                float b0 = 0.f, b1 = 0.f, b2 = 0.f, b3 = 0.f;
#pragma unroll
                for (int i = 0; i < BDD; ++i) {
                    b0 += bb[i] * wnt[i][0]; b1 += bb[i] * wnt[i][1];
                    b2 += bb[i] * wnt[i][2]; b3 += bb[i] * wnt[i][3];
                }
                f0 = fmaxf(f0 + b0, 0.f); f1 = fmaxf(f1 + b1, 0.f);
                f2 = fmaxf(f2 + b2, 0.f); f3 = fmaxf(f3 + b3, 0.f);
            }
            nf[k][0] = f0; nf[k][1] = f1; nf[k][2] = f2; nf[k][3] = f3;
            float s2 = wred64(f0 * w1[0] + f1 * w1[1] + f2 * w1[2] + f3 * w1[3]);
            float s = fmaxf(ss + s2 + bias, 0.f);
            if (jx[k] == LL - 1) s -= 9.0f;
            sc[k] = s;
        }

        float m = sc[0];
#pragma unroll
        for (int k = 1; k < KK; ++k) m = fmaxf(m, sc[k]);
        float e[KK], den = 0.f;
#pragma unroll
        for (int k = 0; k < KK; ++k) { e[k] = expf(sc[k] - m); den += e[k]; }
        float aw[KK], sumaw = 0.f;
#pragma unroll
        for (int k = 0; k < KK; ++k) {
            aw[k] = (jx[k] == LL - 1) ? 0.f : e[k] / den;
            sumaw += aw[k];
        }
        if (lane < KK) {
            float av = aw[0];
#pragma unroll
            for (int k = 1; k < KK; ++k) if (lane == k) av = aw[k];
            awv_out[(size_t)ga * KK + lane] = av;
        }
        if (lane == 0) sw_out[ga] = sumaw;

        short4v wo;
#pragma unroll
        for (int q = 0; q < 4; ++q) {
            float w = 0.f;
#pragma unroll
            for (int k = 0; k < KK; ++k) w += aw[k] * nf[k][q];
            wo[q] = f2bf(w);
        }
        *(short4v*)(wn_out + (size_t)ga * FP + lane * 4) = wo;
    }
}

// ---------------- ctx = relu(WN @ Wa^T + sumaw*ab), LDS-staged B, ks-stagger ----
__global__ __launch_bounds__(512) void k_ctx_mfma(
        const short* __restrict__ XB,      // wn bf16
        const float* __restrict__ SW,
        const short* __restrict__ WaF,     // frag-major (8,16,64,8)
        const float* __restrict__ ab,
        short* __restrict__ ctx_out) {
    __shared__ short lds[2][8192];         // 2 x 16KB
    const int t = threadIdx.x;
    const int wave = t >> 6, lane = t & 63;
    const int abase = blockIdx.x * 32 + (wave >> 2) * 16;
    const int wn4 = wave & 3;
    const int lr = lane & 15, lk = lane >> 4;
    const int kofs = blockIdx.x & 7;

#define CSTAGE(i) do { \
        int ke_ = ((i) + kofs) & 7; \
        _Pragma("unroll") \
        for (int e = 0; e < 2; ++e) { \
            int f = wave * 2 + e; \
            __builtin_amdgcn_global_load_lds( \
                (const __attribute__((address_space(1))) void*)(WaF + (size_t)(ke_ * 16 + f) * 512 + lane * 8), \
                (__attribute__((address_space(3))) void*)(&lds[(i) & 1][f * 512]), 16, 0, 0); \
        } } while (0)

    f32x4 acc[4] = {};
    const short8* xrow = (const short8*)(XB + (size_t)(abase + lr) * FP);

    CSTAGE(0);
#pragma unroll
    for (int i = 0; i < 8; ++i) {
        int ke = (i + kofs) & 7;
        short8 ax = xrow[ke * 4 + lk];
        __syncthreads();
        if (i < 7) CSTAGE(i + 1);
#pragma unroll
        for (int sub = 0; sub < 4; ++sub) {
            int nt = wn4 * 4 + sub;
            short8 bf = *(const short8*)(&lds[i & 1][nt * 512 + lane * 8]);
            acc[sub] = __builtin_amdgcn_mfma_f32_16x16x32_bf16(ax, bf, acc[sub], 0, 0, 0);
        }
    }
#undef CSTAGE

#pragma unroll
    for (int sub = 0; sub < 4; ++sub) {
        int c = wn4 * 64 + sub * 16 + lr;
        float abc = ab[c];
#pragma unroll
        for (int q = 0; q < 4; ++q) {
            int atom = abase + lk * 4 + q;
            float v = acc[sub][q] + SW[atom] * abc;
            ctx_out[(size_t)atom * FP + c] = f2bf(fmaxf(v, 0.f));
        }
    }
}

// ---------------- fused MFMA GRU v5: counted-vmcnt pipeline (T3+T4) -------------
// 512 blocks x 512 thr x 64 atoms. Raw s_barrier (no vmcnt(0) drain) + counted
// asm vmcnt(3): 2 phases of staging loads stay in flight across barriers.
// Triple-buffered B (3x24KB): STAGE(p+2) after barrier p never collides with
// phase p-1 readers. A (ctx,h) staged ONCE in prologue into 64KB LDS with
// XOR-swizzled global source (linear LDS dest; read-side same XOR) ->
// conflict-free ds_read_b128, and the vmcnt queue stays pure (3 loads/phase).
template<int LAST>
__global__ __launch_bounds__(512) void k_gru_mfma(
        const short* __restrict__ XB,     // ctx bf16
        const short* __restrict__ HBl,    // h bf16 (read)
        float* __restrict__ hbuf,         // h fp32 (read old, write new)
        const short* __restrict__ Bih,    // frag-major (8,48,64,8)
        const short* __restrict__ Bhh,
        const float* __restrict__ bih, const float* __restrict__ bhh,
        float* __restrict__ act_out,
        short* __restrict__ HB_out,
        short* __restrict__ ACT_out) {
    __shared__ short ldsB[3][12288];      // 3 x 24 KB
    __shared__ short ldsA[2][16384];      // x,h slabs: 2 x 32 KB (swizzled)
    const int t = threadIdx.x;
    const int wave = t >> 6, lane = t & 63;
    const int rh = wave >> 2;             // row half (32 atoms each)
    const int wn = wave & 3;              // col slice
    const int lr = lane & 15, lk = lane >> 4;
    const int bid = blockIdx.x;
    const int kofs = bid & 7;
    const int abase = bid * 64;

#define PKS(p)  ((((p) >> 2) + kofs) & 7)
#define STAGEP(p) do { \
        const short* base_ = ((((p) >> 1) & 1) ? Bhh : Bih) + (size_t)PKS(p) * 24576; \
        const int h_ = (p) & 1; \
        _Pragma("unroll") \
        for (int e = 0; e < 3; ++e) { \
            int j = wave * 3 + e; \
            int nt = 4 * (j >> 1) + 2 * h_ + (j & 1); \
            __builtin_amdgcn_global_load_lds( \
                (const __attribute__((address_space(1))) void*)(base_ + nt * 512 + lane * 8), \
                (__attribute__((address_space(3))) void*)(&ldsB[(p) % 3][j * 512]), 16, 0, 0); \
        } } while (0)
// swizzled A read: row r, col c (bf16 units); byte = r*512 + c*2, XOR bits 4-6 with r&7
#define LDA_READ(s, r, c) (*(const short8*)((const char*)ldsA[s] + \
        ((((r) * 512 + (c) * 2)) ^ ((((r) & 7)) << 4))))

    // prologue: stage A slabs (64 atoms x 256 cols x bf16, x and h) with
    // pre-swizzled SOURCE so linear LDS dest holds swizzled layout.
    {
        const char* xsrc = (const char*)(XB + (size_t)abase * FP);
        const char* hsrc = (const char*)(HBl + (size_t)abase * FP);
#pragma unroll
        for (int it = 0; it < 4; ++it) {
            int off = it * 8192 + wave * 1024 + lane * 16;
            int src = off ^ (((off >> 9) & 7) << 4);
            __builtin_amdgcn_global_load_lds(
                (const __attribute__((address_space(1))) void*)(xsrc + src),
                (__attribute__((address_space(3))) void*)((char*)ldsA[0] + off), 16, 0, 0);
            __builtin_amdgcn_global_load_lds(
                (const __attribute__((address_space(1))) void*)(hsrc + src),
                (__attribute__((address_space(3))) void*)((char*)ldsA[1] + off), 16, 0, 0);
        }
    }
    STAGEP(0);
    STAGEP(1);
    // outstanding: 8 (A) + 6 (B p0,p1). Loop's vmcnt(3) at p=0 drains A + B(p0).

    f32x4 acc_rz[2][8] = {};   // [rg][g(2)*4+sub]: gi+gh fused
    f32x4 acc_in[2][4] = {};
    f32x4 acc_hn[2][4] = {};

    short8 ax0{}, ah0{}, ax1{}, ah1{};
#pragma unroll
    for (int p = 0; p < 32; ++p) {
        // wait: my phase-p loads done; phase-(p+1) loads stay in flight.
        if (p < 31) { asm volatile("s_waitcnt vmcnt(3)" ::: "memory"); }
        else        { asm volatile("s_waitcnt vmcnt(0)" ::: "memory"); }
        __builtin_amdgcn_s_barrier();            // raw: no implicit drain
        __builtin_amdgcn_sched_barrier(0);       // fence: nothing moves above
        if (p < 30) STAGEP(p + 2);               // buf[(p+2)%3] = buf[(p-1)%3], free after barrier
        const int h_ = p & 1;
        const int mat = (p >> 1) & 1;
        if ((p & 3) == 0) {
            int ks = PKS(p);
            int c = ks * 32 + lk * 8;
            ax0 = LDA_READ(0, rh * 32 + lr, c);
            ah0 = LDA_READ(1, rh * 32 + lr, c);
            ax1 = LDA_READ(0, rh * 32 + 16 + lr, c);
            ah1 = LDA_READ(1, rh * 32 + 16 + lr, c);
        }
#pragma unroll
        for (int rg = 0; rg < 2; ++rg) {
            const short8 a8 = mat ? (rg ? ah1 : ah0) : (rg ? ax1 : ax0);
#pragma unroll
            for (int g = 0; g < 3; ++g) {
#pragma unroll
                for (int s2 = 0; s2 < 2; ++s2) {
                    const int sub = 2 * h_ + s2;
                    const int j = ((4 * g + wn) << 1) | s2;
                    short8 bf = *(const short8*)(&ldsB[p % 3][j * 512 + lane * 8]);
                    if (g < 2)
                        acc_rz[rg][g * 4 + sub] = __builtin_amdgcn_mfma_f32_16x16x32_bf16(a8, bf, acc_rz[rg][g * 4 + sub], 0, 0, 0);
                    else if (mat)
                        acc_hn[rg][sub] = __builtin_amdgcn_mfma_f32_16x16x32_bf16(a8, bf, acc_hn[rg][sub], 0, 0, 0);
                    else
                        acc_in[rg][sub] = __builtin_amdgcn_mfma_f32_16x16x32_bf16(a8, bf, acc_in[rg][sub], 0, 0, 0);
                }
            }
        }
    }
#undef STAGEP
#undef PKS
#undef LDA_READ
    // No trailing barrier needed: HBl was consumed in prologue (LDS copy),
    // epilogue writes touch only this block's atoms.

#pragma unroll
    for (int sub = 0; sub < 4; ++sub) {
        int c = wn * 64 + sub * 16 + lr;
        float brz_r = bih[c] + bhh[c];
        float brz_z = bih[FP + c] + bhh[FP + c];
        float bin_ = bih[2 * FP + c];
        float bhn = bhh[2 * FP + c];
#pragma unroll
        for (int rg = 0; rg < 2; ++rg) {
#pragma unroll
            for (int q = 0; q < 4; ++q) {
                int atom = abase + rh * 32 + rg * 16 + lk * 4 + q;
                size_t idx = (size_t)atom * FP + c;
                float hold = hbuf[idx];
                float r = 1.f / (1.f + expf(-(acc_rz[rg][0 * 4 + sub][q] + brz_r)));
                float z = 1.f / (1.f + expf(-(acc_rz[rg][1 * 4 + sub][q] + brz_z)));
                float n = tanhf(acc_in[rg][sub][q] + bin_ + r * (acc_hn[rg][sub][q] + bhn));
                float hn = (1.f - z) * n + z * hold;
                float rl = fmaxf(hn, 0.f);
                hbuf[idx] = hn;
                act_out[idx] = rl;
                if constexpr (!LAST) {
                    HB_out[idx] = f2bf(hn);
                    ACT_out[idx] = f2bf(rl);
                }
            }
        }
    }
}

// ---------------- mol reductions ----------------
__global__ __launch_bounds__(256) void k_mol_reduce(const float* __restrict__ hbuf,
                                                    const float* __restrict__ act,
                                                    const float* __restrict__ mask,
                                                    float* __restrict__ o_unb0,
                                                    float* __restrict__ o_mfv0,
                                                    float* __restrict__ molF) {
    int b = blockIdx.x, t = threadIdx.x;
    float s1 = 0.f, s2 = 0.f;
    for (int l = 0; l < LL; ++l) {
        float mk = mask[b * LL + l];
        s1 += hbuf[((size_t)b * LL + l) * FP + t] * mk;
        s2 += act[((size_t)b * LL + l) * FP + t] * mk;
    }
    o_unb0[b * FP + t] = s1;
    o_mfv0[b * FP + t] = s2;
    molF[b * FP + t] = s2;
}

// ---------------- AV = act @ mol_attend_W.T + b ----------------
__global__ __launch_bounds__(256) void k_av(const float* __restrict__ act,
                                            const float* __restrict__ MWaT,
                                            const float* __restrict__ mab,
                                            float* __restrict__ AV) {
    int g0 = blockIdx.x * 8;
    int t = threadIdx.x;
    __shared__ float xs[8][FP];
    for (int a = 0; a < 8; ++a) xs[a][t] = act[(size_t)(g0 + a) * FP + t];
    __syncthreads();
    float acc[8];
    float bb2 = mab[t];
#pragma unroll
    for (int a = 0; a < 8; ++a) acc[a] = bb2;
    for (int i = 0; i < FP; ++i) {
        float w = MWaT[i * FP + t];
#pragma unroll
        for (int a = 0; a < 8; ++a) acc[a] += xs[a][i] * w;
    }
    for (int a = 0; a < 8; ++a) AV[(size_t)(g0 + a) * FP + t] = acc[a];
}

// ---------------- mol attention + mol GRU (bf16 weights) ----------------
__global__ __launch_bounds__(256) void k_mol_step(int step,
        const float* __restrict__ act,
        const float* __restrict__ AV,
        float* __restrict__ molF,
        const float* __restrict__ mask,
        const float* __restrict__ mAw, const float* __restrict__ mAb,
        const short* __restrict__ MihB, const short* __restrict__ MhhB,
        const float* __restrict__ mbih, const float* __restrict__ mbhh,
        float* __restrict__ o_mfv, float* __restrict__ o_unb,
        float* __restrict__ o_mawv, float* __restrict__ o_molfeat) {
    int b = blockIdx.x, t = threadIdx.x;
    int wave = t >> 6, lane = t & 63;
    __shared__ float am[FP], hh[FP], cx[FP];
    __shared__ float S2[LL], mw[LL];
    __shared__ float red[4];

    float hprev = molF[b * FP + t];
    hh[t] = hprev;
    am[t] = fmaxf(hprev, 0.f);
    __syncthreads();

    float v = am[t] * mAw[t];
#pragma unroll
    for (int off = 32; off >= 1; off >>= 1) v += __shfl_xor(v, off);
    if (lane == 0) red[wave] = v;
    __syncthreads();
    float s_self = red[0] + red[1] + red[2] + red[3];

    for (int l = wave; l < LL; l += 4) {
        float v2 = 0.f;
#pragma unroll
        for (int q = 0; q < 4; ++q) {
            int i = lane + 64 * q;
            v2 += act[((size_t)b * LL + l) * FP + i] * mAw[FP + i];
        }
#pragma unroll
        for (int off = 32; off >= 1; off >>= 1) v2 += __shfl_xor(v2, off);
        if (lane == 0) S2[l] = v2;
    }
    __syncthreads();

    if (t < LL) {
        float s = fmaxf(s_self + S2[t] + mAb[0], 0.f);
        if (mask[b * LL + t] == 0.f) s += -9e8f;
        S2[t] = s;
    }
    __syncthreads();

    float m = -1e30f;
    for (int l = 0; l < LL; ++l) m = fmaxf(m, S2[l]);
    float den = 0.f;
    for (int l = 0; l < LL; ++l) den += expf(S2[l] - m);
    if (t < LL) {
        float w = expf(S2[t] - m) / den * mask[b * LL + t];
        mw[t] = w;
        o_mawv[(size_t)step * (BB * LL) + b * LL + t] = w;
    }
    __syncthreads();

    float acc = 0.f;
    for (int l = 0; l < LL; ++l) acc += mw[l] * AV[((size_t)b * LL + l) * FP + t];
    cx[t] = fmaxf(acc, 0.f);
    __syncthreads();

    float air = mbih[t], aiz = mbih[FP + t], ain = mbih[2 * FP + t];
    float ahr = mbhh[t], ahz = mbhh[FP + t], ahn = mbhh[2 * FP + t];
    for (int i = 0; i < FP; ++i) {
        float c = cx[i], h = hh[i];
        air += c * bf2f(MihB[i * 768 + t]);
        aiz += c * bf2f(MihB[i * 768 + FP + t]);
        ain += c * bf2f(MihB[i * 768 + 2 * FP + t]);
        ahr += h * bf2f(MhhB[i * 768 + t]);
        ahz += h * bf2f(MhhB[i * 768 + FP + t]);
        ahn += h * bf2f(MhhB[i * 768 + 2 * FP + t]);
    }
    float r = 1.f / (1.f + expf(-(air + ahr)));
    float z = 1.f / (1.f + expf(-(aiz + ahz)));
    float n = tanhf(ain + r * ahn);
    float hn = (1.f - z) * n + z * hprev;

    molF[b * FP + t] = hn;
    o_unb[(size_t)(step + 1) * (BB * FP) + b * FP + t] = hn;
    o_mfv[(size_t)(step + 1) * (BB * FP) + b * FP + t] = fmaxf(hn, 0.f);
    if (step == TT - 1) o_molfeat[b * FP + t] = hn;
}

extern "C" void kernel_launch(void* const* d_in, const int* in_sizes, int n_in,
                              void* d_out, int out_size, void* d_ws, size_t ws_size,
                              hipStream_t stream) {
    const float* atom_list = (const float*)d_in[0];
    const float* bond_list = (const float*)d_in[1];
    const int*   adeg      = (const int*)d_in[2];
    const int*   bdeg      = (const int*)d_in[3];
    const float* amask     = (const float*)d_in[4];
    const float* atom_fc_W = (const float*)d_in[5];
    const float* atom_fc_b = (const float*)d_in[6];
    const float* nfc_W     = (const float*)d_in[7];
    const float* nfc_b     = (const float*)d_in[8];
    const float* gwih      = (const float*)d_in[9];
    const float* gwhh      = (const float*)d_in[10];
    const float* gbih      = (const float*)d_in[11];
    const float* gbhh      = (const float*)d_in[12];
    const float* alW       = (const float*)d_in[13];
    const float* alb       = (const float*)d_in[14];
    const float* atW       = (const float*)d_in[15];
    const float* atb       = (const float*)d_in[16];
    const float* mgwih     = (const float*)d_in[17];
    const float* mgwhh     = (const float*)d_in[18];
    const float* mgbih     = (const float*)d_in[19];
    const float* mgbhh     = (const float*)d_in[20];
    const float* malW      = (const float*)d_in[21];
    const float* malb      = (const float*)d_in[22];
    const float* matW      = (const float*)d_in[23];
    const float* matb      = (const float*)d_in[24];

    const size_t BLF = (size_t)BB * LL * FP;
    float* out = (float*)d_out;
    float* O0 = out;                                 // atom_feature / h (fp32)
    float* O1 = out + BLF;                           // afv (4,B,L,FP)
    float* O2 = O1 + 4 * BLF;                        // awv (3,B,L,K)
    float* O3 = O2 + (size_t)RR * BB * LL * KK;      // mfv
    float* O4 = O3 + (size_t)(TT + 1) * BB * FP;     // mol_unb
    float* O5 = O4 + (size_t)(TT + 1) * BB * FP;     // mawv
    float* O6 = O5 + (size_t)TT * BB * LL;           // mol_feature

    // ws layout
    float* ws = (float*)d_ws;
    short* XB   = (short*)ws;                        // BLF shorts: wn bf16
    short* XB2  = XB + BLF;                          // BLF shorts: ctx bf16
    short* HBb  = XB + 2 * BLF;                      // BLF shorts: h bf16
    short* ACTB = XB + 3 * BLF;                      // BLF shorts: relu(h) bf16
    float* AV   = ws;                                // BLF floats, aliases XB+XB2 (mol phase)
    float* rest = ws + 2 * BLF;
    short* ApreB = (short*)rest;                     // BLF shorts
    float* SW    = rest + BLF / 2;                   // B*L floats
    float* MOLF  = SW + (size_t)BB * LL;
    float* WafcT = MOLF + (size_t)BB * FP;
    float* WnT   = WafcT + AA * FP;
    float* MWaT  = WnT + (AA + BDD) * FP;
    short* MihB  = (short*)(MWaT + (size_t)FP * FP);    // FP*768 shorts
    short* MhhB  = MihB + (size_t)FP * 768;
    short* GW    = MhhB + (size_t)FP * 768;             // RR*2*(8*48*512) shorts
    short* WaF   = GW + (size_t)RR * 2 * 8 * 48 * 512;  // RR*(8*16*512) shorts
    (void)ws_size; (void)in_sizes; (void)n_in; (void)out_size;

    auto tr = [&](const float* src, float* dst, int O, int I) {
        int n = O * I;
        k_transpose<<<(n + 255) / 256, 256, 0, stream>>>(src, dst, O, I);
    };
    tr(atom_fc_W, WafcT, FP, AA);
    tr(nfc_W, WnT, FP, AA + BDD);
    tr(matW, MWaT, FP, FP);

    {
        int n = RR * 2 * 8 * 48 * 512;
        k_prep_gruw<<<(n + 255) / 256, 256, 0, stream>>>(gwih, gwhh, GW);
        int n2 = RR * 8 * 16 * 512;
        k_prep_waf<<<(n2 + 255) / 256, 256, 0, stream>>>(atW, WaF);
        int n3 = FP * 768;
        k_prep_molw<<<(n3 + 255) / 256, 256, 0, stream>>>(mgwih, mgwhh, MihB, MhhB);
    }

    k_atom_fc8<<<BB * LL / 8, 256, 0, stream>>>(atom_list, WafcT, atom_fc_b, O1, O0, HBb);
    k_apre<<<BB * LL / 8, 256, 0, stream>>>(atom_list, WnT, nfc_b, ApreB);

    const size_t wblk = (size_t)8 * 48 * 512;
    const size_t ablk = (size_t)8 * 16 * 512;
    for (int d = 0; d < RR; ++d) {
        const short* selfB = (d == 0) ? HBb : ACTB;
        if (d == 0) {
            k_awn2<1><<<BB * 2, 512, 0, stream>>>(selfB, ApreB, bond_list, adeg, bdeg,
                    WnT, alW, alb, XB, SW, O2);
        } else {
            k_awn2<0><<<BB * 2, 512, 0, stream>>>(selfB, ACTB, bond_list, adeg, bdeg,
                    WnT, alW + (size_t)d * 2 * FP, alb + d,
                    XB, SW, O2 + (size_t)d * BB * LL * KK);
        }
        k_ctx_mfma<<<BB * LL / 32, 512, 0, stream>>>(XB, SW, WaF + (size_t)d * ablk,
                atb + (size_t)d * FP, XB2);
        if (d == RR - 1) {
            k_gru_mfma<1><<<BB * LL / 64, 512, 0, stream>>>(XB2, HBb, O0,
                    GW + (size_t)(d * 2 + 0) * wblk, GW + (size_t)(d * 2 + 1) * wblk,
                    gbih + (size_t)d * 768, gbhh + (size_t)d * 768,
                    O1 + (size_t)(d + 1) * BLF, HBb, ACTB);
        } else {
            k_gru_mfma<0><<<BB * LL / 64, 512, 0, stream>>>(XB2, HBb, O0,
                    GW + (size_t)(d * 2 + 0) * wblk, GW + (size_t)(d * 2 + 1) * wblk,
                    gbih + (size_t)d * 768, gbhh + (size_t)d * 768,
                    O1 + (size_t)(d + 1) * BLF, HBb, ACTB);
        }
    }

    const float* actFin = O1 + (size_t)RR * BLF;
    k_mol_reduce<<<BB, 256, 0, stream>>>(O0, actFin, amask, O4, O3, MOLF);
    k_av<<<BB * LL / 8, 256, 0, stream>>>(actFin, MWaT, matb, AV);
    for (int st = 0; st < TT; ++st) {
        k_mol_step<<<BB, 256, 0, stream>>>(st, actFin, AV, MOLF, amask,
                malW, malb, MihB, MhhB, mgbih, mgbhh,
                O3, O4, O5, O6);
    }
}